// Round 13
// baseline (90.929 us; speedup 1.0000x reference)
//
#include <hip/hip_runtime.h>
#include <hip/hip_bf16.h>

#define C 48
#define HH 192
#define WW 192
#define HP 96
#define WP 96
#define NP 9216   // 96*96

// ws layout (float offsets). Main path total 10,580,096 fl = 42.3 MB (ws ~256 MB).
#define OFF_QB    0         // QB: [9216][16] bf16
#define OFF_KB    36864     // KB: [9216][16] bf16 (pre-scaled by log2e)
#define OFF_VT2   73728     // VT2: [576][64][16] bf16 (row 48=1.0, 49..63=0)
#define OFF_XT    368640    // xT: [9216][48] f32
#define OFF_XTP   811008    // XTP: [98*98][64] bf16 (halo zeroed by pool_wprep)
#define OFF_WB    1118336   // WB: [16][48][64] bf16
#define OFF_PART  1142912   // PART: [288][32][2048] bf16 (32m x 64c partials)
#define WS_NEED_BYTES ((size_t)10580096 * 4)

typedef __attribute__((ext_vector_type(4))) short s16x4;
typedef __attribute__((ext_vector_type(8))) short s16x8;
typedef __attribute__((ext_vector_type(4))) float f32x4;

#if __has_builtin(__builtin_amdgcn_mfma_f32_16x16x16bf16_1k)
static __device__ inline f32x4 mfma16(s16x4 a, s16x4 b, f32x4 c) {
    return __builtin_amdgcn_mfma_f32_16x16x16bf16_1k(a, b, c, 0, 0, 0);
}
#else
static __device__ inline f32x4 mfma16(s16x4 a, s16x4 b, f32x4 c) {
    asm volatile("v_mfma_f32_16x16x16_bf16 %0, %1, %2, %0" : "+v"(c) : "v"(a), "v"(b));
    return c;
}
#endif

static __device__ inline f32x4 mfma32(s16x8 a, s16x8 b, f32x4 c) {
    return __builtin_amdgcn_mfma_f32_16x16x32_bf16(a, b, c, 0, 0, 0);
}

// raw v_exp_f32: computes 2^x (scores pre-scaled by log2e) — proven codegen R4/R8-R12
static __device__ inline float fexp2(float x) {
    float r;
    asm("v_exp_f32 %0, %1" : "=v"(r) : "v"(x));
    return r;
}

static __device__ inline unsigned short f2bf(float f) {
    union { float f; unsigned u; } v; v.f = f;
    unsigned r = v.u + 0x7fff + ((v.u >> 16) & 1);
    return (unsigned short)(r >> 16);
}

static __device__ inline float bf2f(unsigned short u) {
    union { unsigned u; float f; } v; v.u = ((unsigned)u) << 16; return v.f;
}

static __device__ inline s16x4 pack_bf16x4(float a, float b, float c, float d) {
    __hip_bfloat162 h0 = __float22bfloat162_rn(make_float2(a, b));
    __hip_bfloat162 h1 = __float22bfloat162_rn(make_float2(c, d));
    union { unsigned u[2]; s16x4 v; } pu;
    pu.u[0] = *reinterpret_cast<unsigned*>(&h0);
    pu.u[1] = *reinterpret_cast<unsigned*>(&h1);
    return pu.v;
}

// pool (blocks 0..1727) + WB prep + XTP halo zero (blocks 1728..1919)
__global__ void pool_wprep_k(const float* __restrict__ in, float* __restrict__ xT,
                             const float* __restrict__ dw, unsigned short* __restrict__ WB,
                             unsigned short* __restrict__ XTP) {
    int b = blockIdx.x;
    if (b < 1728) {
        int idx = b * 256 + threadIdx.x;
        int c = idx / NP, r = idx % NP;
        int y = r / WP, xx = r % WP;
        const float* p = in + (size_t)c * HH * WW + (2 * y) * WW + 2 * xx;
        xT[(size_t)r * 48 + c] = 0.25f * (p[0] + p[1] + p[WW] + p[WW + 1]);
        return;
    }
    int idx = (b - 1728) * 256 + threadIdx.x;   // 0..49151
    if (idx < 3104) {   // 388 halo positions x 8 threads x 8 c
        int pos = idx >> 3, cc = (idx & 7) * 8;
        int row, col;
        if (pos < 98)       { row = 0;             col = pos; }
        else if (pos < 196) { row = 97;            col = pos - 98; }
        else if (pos < 292) { row = pos - 196 + 1; col = 0; }
        else                { row = pos - 292 + 1; col = 97; }
        s16x8 zz = (s16x8){0, 0, 0, 0, 0, 0, 0, 0};
        *(s16x8*)(XTP + ((size_t)row * 98 + col) * 64 + cc) = zz;
    }
    int ci = idx & 63;
    int co = (idx >> 6) % 48;
    int kidx = idx / (48 * 64);
    float v = (ci < C) ? dw[((size_t)ci * C + co) * 16 + kidx] : 0.f;
    WB[idx] = f2bf(v);
}

// One thread per (position, output): 9216 x 96 = 3456 blocks.
// o<16: q; 16<=o<32: k (L2E-scaled); 32<=o<80: v -> VT2; 80<=o<96: VT2 pad rows.
__global__ void qkvprep_k(const float* __restrict__ xT,
                          const float* __restrict__ qw, const float* __restrict__ qb,
                          const float* __restrict__ kw, const float* __restrict__ kb,
                          const float* __restrict__ vw, const float* __restrict__ vb,
                          unsigned short* __restrict__ QB, unsigned short* __restrict__ KB,
                          unsigned short* __restrict__ VT2) {
    int tid = blockIdx.x * 256 + threadIdx.x;   // 884736
    int p = tid / 96, o = tid % 96;
    int nt = p >> 4, nn = p & 15;
    if (o >= 80) {
        VT2[(size_t)nt * 1024 + (o - 32) * 16 + nn] = (o == 80) ? 0x3F80 : 0;
        return;
    }
    float f[C];
#pragma unroll
    for (int c4 = 0; c4 < C; c4 += 4) {
        f32x4 v = *(const f32x4*)(xT + (size_t)p * 48 + c4);
        f[c4] = v[0]; f[c4 + 1] = v[1]; f[c4 + 2] = v[2]; f[c4 + 3] = v[3];
    }
    if (o < 16) {
        float a = qb[o];
#pragma unroll
        for (int c = 0; c < C; ++c) a += qw[o * C + c] * f[c];
        QB[p * 16 + o] = f2bf(a);
    } else if (o < 32) {
        int oo = o - 16;
        const float L2E = 1.4426950408889634f;
        float a = kb[oo];
#pragma unroll
        for (int c = 0; c < C; ++c) a += kw[oo * C + c] * f[c];
        KB[p * 16 + oo] = f2bf(a * L2E);
    } else {
        int vo = o - 32;
        float a = vb[vo];
#pragma unroll
        for (int c = 0; c < C; ++c) a += vw[vo * C + c] * f[c];
        VT2[(size_t)nt * 1024 + vo * 16 + nn] = f2bf(a);
    }
}

#define MBLKS 72
#define NSPL  32
#define NSTEP 18   // 288 n per split / 16

// R10/R12-proven 32m inner loop (48 VGPR, prefetch, VT2 layout, no LDS)
static __device__ __forceinline__ void attn_core32(const unsigned short* __restrict__ QB,
                                                   const unsigned short* __restrict__ VT2,
                                                   s16x4 bq0, s16x4 bq1, int n0, int lo, int hi,
                                                   f32x4 o0[4], f32x4 o1[4]) {
    const unsigned short* qp = QB + (size_t)(n0 + lo) * 16 + 4 * hi;
    const unsigned short* vp = VT2 + (size_t)(n0 >> 4) * 1024 + lo * 16 + 4 * hi;
    s16x4 aq  = *(const s16x4*)qp;
    s16x4 bv0 = *(const s16x4*)(vp);
    s16x4 bv1 = *(const s16x4*)(vp + 256);
    s16x4 bv2 = *(const s16x4*)(vp + 512);
    s16x4 bv3 = *(const s16x4*)(vp + 768);
    for (int s = 0; s < NSTEP; ++s) {
        qp += 256;
        vp += 1024;
        // prefetch next tile (tail over-read stays inside d_ws; values unused)
        s16x4 aqn  = *(const s16x4*)qp;
        s16x4 bvn0 = *(const s16x4*)(vp);
        s16x4 bvn1 = *(const s16x4*)(vp + 256);
        s16x4 bvn2 = *(const s16x4*)(vp + 512);
        s16x4 bvn3 = *(const s16x4*)(vp + 768);
        f32x4 z = {0.f, 0.f, 0.f, 0.f};
        f32x4 t0 = mfma16(aq, bq0, z);
        f32x4 t1 = mfma16(aq, bq1, z);
        s16x4 p0 = pack_bf16x4(fexp2(t0[0]), fexp2(t0[1]), fexp2(t0[2]), fexp2(t0[3]));
        s16x4 p1 = pack_bf16x4(fexp2(t1[0]), fexp2(t1[1]), fexp2(t1[2]), fexp2(t1[3]));
        o0[0] = mfma16(p0, bv0, o0[0]);
        o0[1] = mfma16(p0, bv1, o0[1]);
        o0[2] = mfma16(p0, bv2, o0[2]);
        o0[3] = mfma16(p0, bv3, o0[3]);
        o1[0] = mfma16(p1, bv0, o1[0]);
        o1[1] = mfma16(p1, bv1, o1[1]);
        o1[2] = mfma16(p1, bv2, o1[2]);
        o1[3] = mfma16(p1, bv3, o1[3]);
        aq = aqn; bv0 = bvn0; bv1 = bvn1; bv2 = bvn2; bv3 = bvn3;
    }
}

// Atomic-free attn: 32m per wave, NSPL=32 n-splits (2304 blocks).
__global__ __launch_bounds__(256) void attn_k(const unsigned short* __restrict__ QB,
                                              const unsigned short* __restrict__ KB,
                                              const unsigned short* __restrict__ VT2,
                                              unsigned short* __restrict__ PART) {
    const int lane = threadIdx.x & 63;
    const int lo = lane & 15, hi = lane >> 4;
    const int wv = threadIdx.x >> 6;
    const int mblk = blockIdx.x % MBLKS;
    const int nspl = blockIdx.x / MBLKS;
    const int mt0 = mblk * 128 + wv * 32;

    const s16x4 bq0 = *(const s16x4*)(KB + (size_t)(mt0 + lo) * 16 + 4 * hi);
    const s16x4 bq1 = *(const s16x4*)(KB + (size_t)(mt0 + 16 + lo) * 16 + 4 * hi);

    f32x4 o0[4], o1[4];
#pragma unroll
    for (int i = 0; i < 4; ++i) {
        o0[i] = (f32x4){0.f, 0.f, 0.f, 0.f};
        o1[i] = (f32x4){0.f, 0.f, 0.f, 0.f};
    }
    attn_core32(QB, VT2, bq0, bq1, nspl * (NP / NSPL), lo, hi, o0, o1);

    unsigned short* cp = PART + ((size_t)(mblk * 4 + wv) * NSPL + nspl) * 2048;
#pragma unroll
    for (int q = 0; q < 8; ++q) {
        const f32x4& o = (q >> 2) ? o1[q & 3] : o0[q & 3];
        s16x4 pk = pack_bf16x4(o[0], o[1], o[2], o[3]);
        *(s16x4*)(cp + q * 256 + lane * 4) = pk;
    }
}

// Reduce 32 chunks + epilogue. 576 blocks = 288 tiles x 2 halves.
__global__ __launch_bounds__(256) void reduce_epi_k(const unsigned short* __restrict__ PART,
                                                    const float* __restrict__ xT,
                                                    const float* __restrict__ gamma,
                                                    unsigned short* __restrict__ XTP) {
    __shared__ float sden[32];
    const int B = blockIdx.x;
    const int T = B >> 1, half = B & 1;
    const int mt0 = (T >> 2) * 128 + (T & 3) * 32;
    const unsigned short* base = PART + (size_t)T * NSPL * 2048;
    const int t = threadIdx.x;

    if (t < 8) {   // den: c=48 -> ct=3, lo=0; groups (h,hi)
        int h = t >> 2, hi = t & 3;
        int idx = (h * 4 + 3) * 256 + (hi * 16) * 4;
        float a0 = 0.f, a1 = 0.f, a2 = 0.f, a3 = 0.f;
        for (int ns = 0; ns < NSPL; ++ns) {
            s16x4 v = *(const s16x4*)(base + ns * 2048 + idx);
            a0 += bf2f((unsigned short)v[0]);
            a1 += bf2f((unsigned short)v[1]);
            a2 += bf2f((unsigned short)v[2]);
            a3 += bf2f((unsigned short)v[3]);
        }
        sden[h * 16 + hi * 4 + 0] = a0;
        sden[h * 16 + hi * 4 + 1] = a1;
        sden[h * 16 + hi * 4 + 2] = a2;
        sden[h * 16 + hi * 4 + 3] = a3;
    }
    __syncthreads();

    float gam = gamma[0];
    int g = half * 256 + t;
    int q = g >> 6, lane = g & 63;
    int h = q >> 2, ct = q & 3;
    int hi = lane >> 4, lo = lane & 15;
    int c = ct * 16 + lo;
    int idx = q * 256 + lane * 4;
    float a0 = 0.f, a1 = 0.f, a2 = 0.f, a3 = 0.f;
    for (int ns = 0; ns < NSPL; ++ns) {
        s16x4 v = *(const s16x4*)(base + ns * 2048 + idx);
        a0 += bf2f((unsigned short)v[0]);
        a1 += bf2f((unsigned short)v[1]);
        a2 += bf2f((unsigned short)v[2]);
        a3 += bf2f((unsigned short)v[3]);
    }
    if (c < 48) {
        float av[4] = {a0, a1, a2, a3};
#pragma unroll
        for (int j = 0; j < 4; ++j) {
            int ml = h * 16 + hi * 4 + j;
            int m = mt0 + ml;
            float val = gam * av[j] / sden[ml] + xT[(size_t)m * 48 + c];
            int iy = m / WP, ix = m % WP;
            XTP[((size_t)(iy + 1) * 98 + ix + 1) * 64 + c] = f2bf(val);
        }
    }
}

// ---------- fallback path (small ws): atomics into O4 (overlays PART) ----------
__global__ __launch_bounds__(256) void attn_atomic_k(const unsigned short* __restrict__ QB,
                                                     const unsigned short* __restrict__ KB,
                                                     const unsigned short* __restrict__ VT2,
                                                     float* __restrict__ O4) {
    const int lane = threadIdx.x & 63;
    const int lo = lane & 15, hi = lane >> 4;
    const int wv = threadIdx.x >> 6;
    const int mblk = blockIdx.x % 72;
    const int nspl = blockIdx.x / 72;
    const int mt0 = mblk * 128 + wv * 32;
    const s16x4 bq0 = *(const s16x4*)(KB + (size_t)(mt0 + lo) * 16 + 4 * hi);
    const s16x4 bq1 = *(const s16x4*)(KB + (size_t)(mt0 + 16 + lo) * 16 + 4 * hi);
    f32x4 o0[4], o1[4];
#pragma unroll
    for (int i = 0; i < 4; ++i) {
        o0[i] = (f32x4){0.f, 0.f, 0.f, 0.f};
        o1[i] = (f32x4){0.f, 0.f, 0.f, 0.f};
    }
    attn_core32(QB, VT2, bq0, bq1, nspl * 288, lo, hi, o0, o1);
    float* Oc = O4 + (size_t)(nspl & 3) * (NP * 64);
#pragma unroll
    for (int ct = 0; ct < 4; ++ct)
#pragma unroll
        for (int j = 0; j < 4; ++j) {
            atomicAdd(&Oc[(size_t)(mt0 + 4 * hi + j) * 64 + 16 * ct + lo], o0[ct][j]);
            atomicAdd(&Oc[(size_t)(mt0 + 16 + 4 * hi + j) * 64 + 16 * ct + lo], o1[ct][j]);
        }
}

__global__ void epi_atomic_k(const float* __restrict__ O4, const float* __restrict__ xT,
                             const float* __restrict__ gamma, unsigned short* __restrict__ XTP) {
    int m = blockIdx.x * 256 + threadIdx.x;
    if (m >= NP) return;
    int iy = m / WP, ix = m % WP;
    unsigned short* xp = XTP + ((size_t)(iy + 1) * 98 + ix + 1) * 64;
    float den = 0.f;
#pragma unroll
    for (int cp = 0; cp < 4; ++cp) den += O4[(size_t)cp * (NP * 64) + (size_t)m * 64 + 48];
    float rg = gamma[0] / den;
#pragma unroll
    for (int c = 0; c < C; ++c) {
        float o = 0.f;
#pragma unroll
        for (int cp = 0; cp < 4; ++cp) o += O4[(size_t)cp * (NP * 64) + (size_t)m * 64 + c];
        xp[c] = f2bf(rg * o + xT[(size_t)m * 48 + c]);
    }
}

// ConvTranspose2d via MFMA; one 16-ox tile per wave (1152 blocks).
__global__ __launch_bounds__(128) void convt_mfma_k(const unsigned short* __restrict__ XTP,
                                                    const unsigned short* __restrict__ WB,
                                                    const float* __restrict__ db,
                                                    float* __restrict__ y) {
    const int lane = threadIdx.x & 63;
    const int lo = lane & 15, hi = lane >> 4;
    const int wv = threadIdx.x >> 6;   // 0..1
    const int b = blockIdx.x;          // 96*2*2*3
    const int i3 = b % 3;
    const int r3 = b / 3;
    const int px = r3 & 1;
    const int py = (r3 >> 1) & 1;
    const int oyp = r3 >> 2;

    const int sy[2] = {0, py ? 1 : -1};
    const int kyt[2] = {py ? 2 : 1, py ? 0 : 3};
    const int sx[2] = {0, px ? 1 : -1};
    const int kxt[2] = {px ? 2 : 1, px ? 0 : 3};

    s16x8 bw[2][2][2][3];  // [ty][tx][kk][ct]
#pragma unroll
    for (int ty = 0; ty < 2; ++ty)
#pragma unroll
        for (int tx = 0; tx < 2; ++tx) {
            const unsigned short* wp = WB + (size_t)(kyt[ty] * 4 + kxt[tx]) * 48 * 64;
#pragma unroll
            for (int kk = 0; kk < 2; ++kk)
#pragma unroll
                for (int ct = 0; ct < 3; ++ct)
                    bw[ty][tx][kk][ct] = *(const s16x8*)(wp + (size_t)(ct * 16 + lo) * 64 + kk * 32 + 8 * hi);
        }
    float bias[3];
#pragma unroll
    for (int ct = 0; ct < 3; ++ct) bias[ct] = db[ct * 16 + lo];

    const int oy = 2 * oyp + py;
    const int ox0 = (wv * 3 + i3) * 16;
    f32x4 acc[3];
#pragma unroll
    for (int ct = 0; ct < 3; ++ct) acc[ct] = (f32x4){bias[ct], bias[ct], bias[ct], bias[ct]};
#pragma unroll
    for (int ty = 0; ty < 2; ++ty) {
        int R0 = (oyp + sy[ty] + 1) * 98;
#pragma unroll
        for (int tx = 0; tx < 2; ++tx) {
            const unsigned short* ap = XTP + (size_t)(R0 + ox0 + sx[tx] + 1 + lo) * 64 + 8 * hi;
#pragma unroll
            for (int kk = 0; kk < 2; ++kk) {
                s16x8 a = *(const s16x8*)(ap + kk * 32);
                acc[0] = mfma32(a, bw[ty][tx][kk][0], acc[0]);
                acc[1] = mfma32(a, bw[ty][tx][kk][1], acc[1]);
                acc[2] = mfma32(a, bw[ty][tx][kk][2], acc[2]);
            }
        }
    }
#pragma unroll
    for (int ct = 0; ct < 3; ++ct)
#pragma unroll
        for (int j = 0; j < 4; ++j)
            y[(size_t)(ct * 16 + lo) * (HH * WW) + oy * WW + 2 * (ox0 + 4 * hi + j) + px] = acc[ct][j];
}

extern "C" void kernel_launch(void* const* d_in, const int* in_sizes, int n_in,
                              void* d_out, int out_size, void* d_ws, size_t ws_size,
                              hipStream_t stream) {
    const float* in    = (const float*)d_in[0];
    const float* qw    = (const float*)d_in[1];
    const float* qb    = (const float*)d_in[2];
    const float* kw    = (const float*)d_in[3];
    const float* kb    = (const float*)d_in[4];
    const float* vw    = (const float*)d_in[5];
    const float* vb    = (const float*)d_in[6];
    const float* gamma = (const float*)d_in[7];
    const float* dw    = (const float*)d_in[8];
    const float* db    = (const float*)d_in[9];
    float* out = (float*)d_out;

    float* ws = (float*)d_ws;
    unsigned short* QB   = (unsigned short*)(ws + OFF_QB);
    unsigned short* KB   = (unsigned short*)(ws + OFF_KB);
    unsigned short* VT2  = (unsigned short*)(ws + OFF_VT2);
    float*          xT   = ws + OFF_XT;
    unsigned short* XTP  = (unsigned short*)(ws + OFF_XTP);
    unsigned short* WB   = (unsigned short*)(ws + OFF_WB);
    unsigned short* PART = (unsigned short*)(ws + OFF_PART);

    pool_wprep_k<<<1920, 256, 0, stream>>>(in, xT, dw, WB, XTP);
    qkvprep_k<<<3456, 256, 0, stream>>>(xT, qw, qb, kw, kb, vw, vb, QB, KB, VT2);

    if (ws_size >= WS_NEED_BYTES) {
        attn_k<<<MBLKS * NSPL, 256, 0, stream>>>(QB, KB, VT2, PART);
        reduce_epi_k<<<576, 256, 0, stream>>>(PART, xT, gamma, XTP);
    } else {
        float* O4 = (float*)PART;   // overlays PART region
        hipMemsetAsync(O4, 0, (size_t)4 * NP * 64 * sizeof(float), stream);
        attn_atomic_k<<<72 * 32, 256, 0, stream>>>(QB, KB, VT2, O4);
        epi_atomic_k<<<(NP + 255) / 256, 256, 0, stream>>>(O4, xT, gamma, XTP);
    }
    convt_mfma_k<<<96 * 2 * 2 * 3, 128, 0, stream>>>(XTP, WB, db, out);
}

// Round 15
// 84.762 us; speedup vs baseline: 1.0728x; 1.0728x over previous
//
#include <hip/hip_runtime.h>
#include <hip/hip_bf16.h>

#define C 48
#define HH 192
#define WW 192
#define HP 96
#define WP 96
#define NP 9216   // 96*96

// ws layout (float offsets) — sizes RE-DERIVED AND CHECKED:
//  QB  [9216][16] bf16  = 147456 us = 73728 fl   @ 0        .. 73728
//  KB  [9216][16] bf16  = 147456 us = 73728 fl   @ 73728    .. 147456
//  VT2 [576][64][16] bf16 = 589824 us = 294912 fl @ 147456  .. 442368
//  xT  [9216][48] f32   = 442368 fl              @ 442368   .. 884736
//  XTP [98*98][64] bf16 = 614656 us = 307328 fl  @ 884736   .. 1192064
//  WB  [16][48][64] bf16 = 49152 us = 24576 fl   @ 1192064  .. 1216640
//  PART[288][16][2048] bf16 = 9437184 us = 4718592 fl @ 1216640 .. 5935232
#define OFF_QB    0
#define OFF_KB    73728
#define OFF_VT2   147456
#define OFF_XT    442368
#define OFF_XTP   884736
#define OFF_WB    1192064
#define OFF_PART  1216640
#define WS_NEED_BYTES ((size_t)5935232 * 4)   // 23,740,928 B (proven fits in R5-R7 era)

typedef __attribute__((ext_vector_type(4))) short s16x4;
typedef __attribute__((ext_vector_type(8))) short s16x8;
typedef __attribute__((ext_vector_type(4))) float f32x4;

#if __has_builtin(__builtin_amdgcn_mfma_f32_16x16x16bf16_1k)
static __device__ inline f32x4 mfma16(s16x4 a, s16x4 b, f32x4 c) {
    return __builtin_amdgcn_mfma_f32_16x16x16bf16_1k(a, b, c, 0, 0, 0);
}
#else
static __device__ inline f32x4 mfma16(s16x4 a, s16x4 b, f32x4 c) {
    asm volatile("v_mfma_f32_16x16x16_bf16 %0, %1, %2, %0" : "+v"(c) : "v"(a), "v"(b));
    return c;
}
#endif

static __device__ inline f32x4 mfma32(s16x8 a, s16x8 b, f32x4 c) {
    return __builtin_amdgcn_mfma_f32_16x16x32_bf16(a, b, c, 0, 0, 0);
}

// raw v_exp_f32: computes 2^x (scores pre-scaled by log2e) — proven codegen R4/R8-R13
static __device__ inline float fexp2(float x) {
    float r;
    asm("v_exp_f32 %0, %1" : "=v"(r) : "v"(x));
    return r;
}

static __device__ inline unsigned short f2bf(float f) {
    union { float f; unsigned u; } v; v.f = f;
    unsigned r = v.u + 0x7fff + ((v.u >> 16) & 1);
    return (unsigned short)(r >> 16);
}

static __device__ inline float bf2f(unsigned short u) {
    union { unsigned u; float f; } v; v.u = ((unsigned)u) << 16; return v.f;
}

static __device__ inline s16x4 pack_bf16x4(float a, float b, float c, float d) {
    __hip_bfloat162 h0 = __float22bfloat162_rn(make_float2(a, b));
    __hip_bfloat162 h1 = __float22bfloat162_rn(make_float2(c, d));
    union { unsigned u[2]; s16x4 v; } pu;
    pu.u[0] = *reinterpret_cast<unsigned*>(&h0);
    pu.u[1] = *reinterpret_cast<unsigned*>(&h1);
    return pu.v;
}

// pooled residual, transposed: xT[p][c]
__global__ void pool_k(const float* __restrict__ in, float* __restrict__ xT) {
    int idx = blockIdx.x * 256 + threadIdx.x;
    if (idx >= C * NP) return;
    int c = idx / NP, r = idx % NP;
    int y = r / WP, xx = r % WP;
    const float* p = in + (size_t)c * HH * WW + (2 * y) * WW + 2 * xx;
    xT[(size_t)r * 48 + c] = 0.25f * (p[0] + p[1] + p[WW] + p[WW + 1]);
}

// 5-group prep: g0->QB, g1->KB(+VT2 pad rows), g2..4->VT2 v-rows
__global__ void qkvprep_k(const float* __restrict__ xT,
                          const float* __restrict__ qw, const float* __restrict__ qb,
                          const float* __restrict__ kw, const float* __restrict__ kb,
                          const float* __restrict__ vw, const float* __restrict__ vb,
                          unsigned short* __restrict__ QB, unsigned short* __restrict__ KB,
                          unsigned short* __restrict__ VT2) {
    int tid = blockIdx.x * 256 + threadIdx.x;   // 5*9216 threads
    int p = tid % NP;
    int g = tid / NP;
    float f[C];
#pragma unroll
    for (int c4 = 0; c4 < C; c4 += 4) {
        f32x4 v = *(const f32x4*)(xT + (size_t)p * 48 + c4);
        f[c4] = v[0]; f[c4 + 1] = v[1]; f[c4 + 2] = v[2]; f[c4 + 3] = v[3];
    }
    int nt = p >> 4, nn = p & 15;
    if (g == 0) {
#pragma unroll
        for (int o = 0; o < 16; ++o) {
            float a = qb[o];
#pragma unroll
            for (int c = 0; c < C; ++c) a += qw[o * C + c] * f[c];
            QB[p * 16 + o] = f2bf(a);
        }
    } else if (g == 1) {
        const float L2E = 1.4426950408889634f;
#pragma unroll
        for (int o = 0; o < 16; ++o) {
            float a = kb[o];
#pragma unroll
            for (int c = 0; c < C; ++c) a += kw[o * C + c] * f[c];
            KB[p * 16 + o] = f2bf(a * L2E);
        }
        VT2[(size_t)nt * 1024 + 48 * 16 + nn] = 0x3F80;  // row 48 = ones (den)
#pragma unroll
        for (int r = 49; r < 64; ++r) VT2[(size_t)nt * 1024 + r * 16 + nn] = 0;
    } else {
        int c0 = (g - 2) * 16;
#pragma unroll
        for (int oo = 0; oo < 16; ++oo) {
            int o = c0 + oo;
            float a = vb[o];
#pragma unroll
            for (int c = 0; c < C; ++c) a += vw[o * C + c] * f[c];
            VT2[(size_t)nt * 1024 + o * 16 + nn] = f2bf(a);
        }
    }
}

#define MBLKS 72
#define NSPL  16
#define NSTEP 36   // 576 n per wave / 16

// 2-deep software pipeline: loads issued 2 steps ahead of use.
// Tail over-reads (up to 2 tiles) stay inside d_ws (QB->KB, VT2->xT); values unused.
template<int STEPS>
static __device__ __forceinline__ void attn_core32(const unsigned short* __restrict__ QB,
                                                   const unsigned short* __restrict__ VT2,
                                                   s16x4 bq0, s16x4 bq1, int n0, int lo, int hi,
                                                   f32x4 o0[4], f32x4 o1[4]) {
    const unsigned short* qp = QB + (size_t)(n0 + lo) * 16 + 4 * hi;
    const unsigned short* vp = VT2 + (size_t)(n0 >> 4) * 1024 + lo * 16 + 4 * hi;
    // stage A (t0)
    s16x4 aqA  = *(const s16x4*)qp;
    s16x4 bvA0 = *(const s16x4*)(vp);
    s16x4 bvA1 = *(const s16x4*)(vp + 256);
    s16x4 bvA2 = *(const s16x4*)(vp + 512);
    s16x4 bvA3 = *(const s16x4*)(vp + 768);
    // stage B (t1)
    qp += 256; vp += 1024;
    s16x4 aqB  = *(const s16x4*)qp;
    s16x4 bvB0 = *(const s16x4*)(vp);
    s16x4 bvB1 = *(const s16x4*)(vp + 256);
    s16x4 bvB2 = *(const s16x4*)(vp + 512);
    s16x4 bvB3 = *(const s16x4*)(vp + 768);

    for (int s = 0; s < STEPS; ++s) {
        qp += 256; vp += 1024;
        // issue loads for t(s+2)
        s16x4 aqn  = *(const s16x4*)qp;
        s16x4 bvn0 = *(const s16x4*)(vp);
        s16x4 bvn1 = *(const s16x4*)(vp + 256);
        s16x4 bvn2 = *(const s16x4*)(vp + 512);
        s16x4 bvn3 = *(const s16x4*)(vp + 768);

        // compute t(s) from stage A
        f32x4 z = {0.f, 0.f, 0.f, 0.f};
        f32x4 t0 = mfma16(aqA, bq0, z);
        f32x4 t1 = mfma16(aqA, bq1, z);
        s16x4 p0 = pack_bf16x4(fexp2(t0[0]), fexp2(t0[1]), fexp2(t0[2]), fexp2(t0[3]));
        s16x4 p1 = pack_bf16x4(fexp2(t1[0]), fexp2(t1[1]), fexp2(t1[2]), fexp2(t1[3]));
        o0[0] = mfma16(p0, bvA0, o0[0]);
        o0[1] = mfma16(p0, bvA1, o0[1]);
        o0[2] = mfma16(p0, bvA2, o0[2]);
        o0[3] = mfma16(p0, bvA3, o0[3]);
        o1[0] = mfma16(p1, bvA0, o1[0]);
        o1[1] = mfma16(p1, bvA1, o1[1]);
        o1[2] = mfma16(p1, bvA2, o1[2]);
        o1[3] = mfma16(p1, bvA3, o1[3]);

        // rotate stages: B -> A, new -> B
        aqA = aqB; bvA0 = bvB0; bvA1 = bvB1; bvA2 = bvB2; bvA3 = bvB3;
        aqB = aqn; bvB0 = bvn0; bvB1 = bvn1; bvB2 = bvn2; bvB3 = bvn3;
    }
}

// Atomic-free attn: 32m per wave, NSPL=16 n-splits (1152 blocks).
__global__ __launch_bounds__(256, 2) void attn_k(const unsigned short* __restrict__ QB,
                                                 const unsigned short* __restrict__ KB,
                                                 const unsigned short* __restrict__ VT2,
                                                 unsigned short* __restrict__ PART) {
    const int lane = threadIdx.x & 63;
    const int lo = lane & 15, hi = lane >> 4;
    const int wv = threadIdx.x >> 6;
    const int mblk = blockIdx.x % MBLKS;
    const int nspl = blockIdx.x / MBLKS;
    const int mt0 = mblk * 128 + wv * 32;

    const s16x4 bq0 = *(const s16x4*)(KB + (size_t)(mt0 + lo) * 16 + 4 * hi);
    const s16x4 bq1 = *(const s16x4*)(KB + (size_t)(mt0 + 16 + lo) * 16 + 4 * hi);

    f32x4 o0[4], o1[4];
#pragma unroll
    for (int i = 0; i < 4; ++i) {
        o0[i] = (f32x4){0.f, 0.f, 0.f, 0.f};
        o1[i] = (f32x4){0.f, 0.f, 0.f, 0.f};
    }
    attn_core32<NSTEP>(QB, VT2, bq0, bq1, nspl * (NP / NSPL), lo, hi, o0, o1);

    unsigned short* cp = PART + ((size_t)(mblk * 4 + wv) * NSPL + nspl) * 2048;
#pragma unroll
    for (int q = 0; q < 8; ++q) {
        const f32x4& o = (q >> 2) ? o1[q & 3] : o0[q & 3];
        s16x4 pk = pack_bf16x4(o[0], o[1], o[2], o[3]);
        *(s16x4*)(cp + q * 256 + lane * 4) = pk;
    }
}

// Reduce 16 chunks + epilogue. One block per 32-m tile (288 blocks).
__global__ __launch_bounds__(256) void reduce_epi_k(const unsigned short* __restrict__ PART,
                                                    const float* __restrict__ xT,
                                                    const float* __restrict__ gamma,
                                                    unsigned short* __restrict__ XTP) {
    __shared__ float sden[32];
    const int T = blockIdx.x;          // 288 tiles
    const int mt0 = (T >> 2) * 128 + (T & 3) * 32;
    const unsigned short* base = PART + (size_t)T * NSPL * 2048;
    const int t = threadIdx.x;

    if (t < 8) {   // den: c=48 -> ct=3, lo=0; groups (h,hi)
        int h = t >> 2, hi = t & 3;
        int idx = (h * 4 + 3) * 256 + (hi * 16) * 4;
        float a0 = 0.f, a1 = 0.f, a2 = 0.f, a3 = 0.f;
        for (int ns = 0; ns < NSPL; ++ns) {
            s16x4 v = *(const s16x4*)(base + ns * 2048 + idx);
            a0 += bf2f((unsigned short)v[0]);
            a1 += bf2f((unsigned short)v[1]);
            a2 += bf2f((unsigned short)v[2]);
            a3 += bf2f((unsigned short)v[3]);
        }
        sden[h * 16 + hi * 4 + 0] = a0;
        sden[h * 16 + hi * 4 + 1] = a1;
        sden[h * 16 + hi * 4 + 2] = a2;
        sden[h * 16 + hi * 4 + 3] = a3;
    }
    __syncthreads();

    float gam = gamma[0];
#pragma unroll
    for (int g = t; g < 512; g += 256) {
        int q = g >> 6, lane = g & 63;
        int h = q >> 2, ct = q & 3;
        int hi = lane >> 4, lo = lane & 15;
        int c = ct * 16 + lo;
        int idx = q * 256 + lane * 4;
        float a0 = 0.f, a1 = 0.f, a2 = 0.f, a3 = 0.f;
        for (int ns = 0; ns < NSPL; ++ns) {
            s16x4 v = *(const s16x4*)(base + ns * 2048 + idx);
            a0 += bf2f((unsigned short)v[0]);
            a1 += bf2f((unsigned short)v[1]);
            a2 += bf2f((unsigned short)v[2]);
            a3 += bf2f((unsigned short)v[3]);
        }
        if (c < 48) {
            float av[4] = {a0, a1, a2, a3};
#pragma unroll
            for (int j = 0; j < 4; ++j) {
                int ml = h * 16 + hi * 4 + j;
                int m = mt0 + ml;
                float val = gam * av[j] / sden[ml] + xT[(size_t)m * 48 + c];
                int iy = m / WP, ix = m % WP;
                XTP[((size_t)(iy + 1) * 98 + ix + 1) * 64 + c] = f2bf(val);
            }
        }
    }
}

// ---------- fallback path (small ws): atomics into O4 (overlays PART) ----------
__global__ __launch_bounds__(256) void attn_atomic_k(const unsigned short* __restrict__ QB,
                                                     const unsigned short* __restrict__ KB,
                                                     const unsigned short* __restrict__ VT2,
                                                     float* __restrict__ O4) {
    const int lane = threadIdx.x & 63;
    const int lo = lane & 15, hi = lane >> 4;
    const int wv = threadIdx.x >> 6;
    const int mblk = blockIdx.x % 72;
    const int nspl = blockIdx.x / 72;
    const int mt0 = mblk * 128 + wv * 32;
    const s16x4 bq0 = *(const s16x4*)(KB + (size_t)(mt0 + lo) * 16 + 4 * hi);
    const s16x4 bq1 = *(const s16x4*)(KB + (size_t)(mt0 + 16 + lo) * 16 + 4 * hi);
    f32x4 o0[4], o1[4];
#pragma unroll
    for (int i = 0; i < 4; ++i) {
        o0[i] = (f32x4){0.f, 0.f, 0.f, 0.f};
        o1[i] = (f32x4){0.f, 0.f, 0.f, 0.f};
    }
    attn_core32<18>(QB, VT2, bq0, bq1, nspl * 288, lo, hi, o0, o1);
    float* Oc = O4 + (size_t)(nspl & 3) * (NP * 64);
#pragma unroll
    for (int ct = 0; ct < 4; ++ct)
#pragma unroll
        for (int j = 0; j < 4; ++j) {
            atomicAdd(&Oc[(size_t)(mt0 + 4 * hi + j) * 64 + 16 * ct + lo], o0[ct][j]);
            atomicAdd(&Oc[(size_t)(mt0 + 16 + 4 * hi + j) * 64 + 16 * ct + lo], o1[ct][j]);
        }
}

__global__ void epi_atomic_k(const float* __restrict__ O4, const float* __restrict__ xT,
                             const float* __restrict__ gamma, unsigned short* __restrict__ XTP) {
    int m = blockIdx.x * 256 + threadIdx.x;
    if (m >= NP) return;
    int iy = m / WP, ix = m % WP;
    unsigned short* xp = XTP + ((size_t)(iy + 1) * 98 + ix + 1) * 64;
    float den = 0.f;
#pragma unroll
    for (int cp = 0; cp < 4; ++cp) den += O4[(size_t)cp * (NP * 64) + (size_t)m * 64 + 48];
    float rg = gamma[0] / den;
#pragma unroll
    for (int c = 0; c < C; ++c) {
        float o = 0.f;
#pragma unroll
        for (int cp = 0; cp < 4; ++cp) o += O4[(size_t)cp * (NP * 64) + (size_t)m * 64 + c];
        xp[c] = f2bf(rg * o + xT[(size_t)m * 48 + c]);
    }
}

// WB prep + XTP halo zeroing (no full-XTP memset dispatch).
__global__ void wprep_k(const float* __restrict__ dw, unsigned short* __restrict__ WB,
                        unsigned short* __restrict__ XTP) {
    int idx = blockIdx.x * 256 + threadIdx.x;
    if (idx < 3104) {   // 388 halo positions x 8 threads x 8 c
        int pos = idx >> 3, cc = (idx & 7) * 8;
        int row, col;
        if (pos < 98)       { row = 0;             col = pos; }
        else if (pos < 196) { row = 97;            col = pos - 98; }
        else if (pos < 292) { row = pos - 196 + 1; col = 0; }
        else                { row = pos - 292 + 1; col = 97; }
        s16x8 zz = (s16x8){0, 0, 0, 0, 0, 0, 0, 0};
        *(s16x8*)(XTP + ((size_t)row * 98 + col) * 64 + cc) = zz;
    }
    if (idx >= 16 * 48 * 64) return;
    int ci = idx & 63;
    int co = (idx >> 6) % 48;
    int kidx = idx / (48 * 64);
    float v = (ci < C) ? dw[((size_t)ci * C + co) * 16 + kidx] : 0.f;
    WB[idx] = f2bf(v);
}

// ConvTranspose2d via MFMA; one 16-ox tile per wave (1152 blocks).
__global__ __launch_bounds__(128) void convt_mfma_k(const unsigned short* __restrict__ XTP,
                                                    const unsigned short* __restrict__ WB,
                                                    const float* __restrict__ db,
                                                    float* __restrict__ y) {
    const int lane = threadIdx.x & 63;
    const int lo = lane & 15, hi = lane >> 4;
    const int wv = threadIdx.x >> 6;   // 0..1
    const int b = blockIdx.x;          // 96*2*2*3
    const int i3 = b % 3;
    const int r3 = b / 3;
    const int px = r3 & 1;
    const int py = (r3 >> 1) & 1;
    const int oyp = r3 >> 2;

    const int sy[2] = {0, py ? 1 : -1};
    const int kyt[2] = {py ? 2 : 1, py ? 0 : 3};
    const int sx[2] = {0, px ? 1 : -1};
    const int kxt[2] = {px ? 2 : 1, px ? 0 : 3};

    s16x8 bw[2][2][2][3];  // [ty][tx][kk][ct]
#pragma unroll
    for (int ty = 0; ty < 2; ++ty)
#pragma unroll
        for (int tx = 0; tx < 2; ++tx) {
            const unsigned short* wp = WB + (size_t)(kyt[ty] * 4 + kxt[tx]) * 48 * 64;
#pragma unroll
            for (int kk = 0; kk < 2; ++kk)
#pragma unroll
                for (int ct = 0; ct < 3; ++ct)
                    bw[ty][tx][kk][ct] = *(const s16x8*)(wp + (size_t)(ct * 16 + lo) * 64 + kk * 32 + 8 * hi);
        }
    float bias[3];
#pragma unroll
    for (int ct = 0; ct < 3; ++ct) bias[ct] = db[ct * 16 + lo];

    const int oy = 2 * oyp + py;
    const int ox0 = (wv * 3 + i3) * 16;
    f32x4 acc[3];
#pragma unroll
    for (int ct = 0; ct < 3; ++ct) acc[ct] = (f32x4){bias[ct], bias[ct], bias[ct], bias[ct]};
#pragma unroll
    for (int ty = 0; ty < 2; ++ty) {
        int R0 = (oyp + sy[ty] + 1) * 98;
#pragma unroll
        for (int tx = 0; tx < 2; ++tx) {
            const unsigned short* ap = XTP + (size_t)(R0 + ox0 + sx[tx] + 1 + lo) * 64 + 8 * hi;
#pragma unroll
            for (int kk = 0; kk < 2; ++kk) {
                s16x8 a = *(const s16x8*)(ap + kk * 32);
                acc[0] = mfma32(a, bw[ty][tx][kk][0], acc[0]);
                acc[1] = mfma32(a, bw[ty][tx][kk][1], acc[1]);
                acc[2] = mfma32(a, bw[ty][tx][kk][2], acc[2]);
            }
        }
    }
#pragma unroll
    for (int ct = 0; ct < 3; ++ct)
#pragma unroll
        for (int j = 0; j < 4; ++j)
            y[(size_t)(ct * 16 + lo) * (HH * WW) + oy * WW + 2 * (ox0 + 4 * hi + j) + px] = acc[ct][j];
}

extern "C" void kernel_launch(void* const* d_in, const int* in_sizes, int n_in,
                              void* d_out, int out_size, void* d_ws, size_t ws_size,
                              hipStream_t stream) {
    const float* in    = (const float*)d_in[0];
    const float* qw    = (const float*)d_in[1];
    const float* qb    = (const float*)d_in[2];
    const float* kw    = (const float*)d_in[3];
    const float* kb    = (const float*)d_in[4];
    const float* vw    = (const float*)d_in[5];
    const float* vb    = (const float*)d_in[6];
    const float* gamma = (const float*)d_in[7];
    const float* dw    = (const float*)d_in[8];
    const float* db    = (const float*)d_in[9];
    float* out = (float*)d_out;

    float* ws = (float*)d_ws;
    unsigned short* QB   = (unsigned short*)(ws + OFF_QB);
    unsigned short* KB   = (unsigned short*)(ws + OFF_KB);
    unsigned short* VT2  = (unsigned short*)(ws + OFF_VT2);
    float*          xT   = ws + OFF_XT;
    unsigned short* XTP  = (unsigned short*)(ws + OFF_XTP);
    unsigned short* WB   = (unsigned short*)(ws + OFF_WB);
    unsigned short* PART = (unsigned short*)(ws + OFF_PART);

    pool_k<<<(C * NP + 255) / 256, 256, 0, stream>>>(in, xT);
    qkvprep_k<<<(5 * NP) / 256, 256, 0, stream>>>(xT, qw, qb, kw, kb, vw, vb, QB, KB, VT2);
    wprep_k<<<(16 * 48 * 64) / 256, 256, 0, stream>>>(dw, WB, XTP);

    if (ws_size >= WS_NEED_BYTES) {
        attn_k<<<MBLKS * NSPL, 256, 0, stream>>>(QB, KB, VT2, PART);
        reduce_epi_k<<<288, 256, 0, stream>>>(PART, xT, gamma, XTP);
    } else {
        float* O4 = (float*)PART;   // overlays PART region
        hipMemsetAsync(O4, 0, (size_t)4 * NP * 64 * sizeof(float), stream);
        attn_atomic_k<<<72 * 32, 256, 0, stream>>>(QB, KB, VT2, O4);
        epi_atomic_k<<<(NP + 255) / 256, 256, 0, stream>>>(O4, xT, gamma, XTP);
    }
    convt_mfma_k<<<96 * 2 * 2 * 3, 128, 0, stream>>>(XTP, WB, db, out);
}

// Round 17
// 82.943 us; speedup vs baseline: 1.0963x; 1.0219x over previous
//
#include <hip/hip_runtime.h>
#include <hip/hip_bf16.h>

#define C 48
#define HH 192
#define WW 192
#define HP 96
#define WP 96
#define NP 9216   // 96*96

// ws layout (float offsets) — checked sizes (R15-proven)
#define OFF_QB    0         // QB  [9216][16] bf16  -> 73728 fl
#define OFF_KB    73728     // KB  [9216][16] bf16  -> 73728 fl
#define OFF_VT2   147456    // VT2 [576][64][16] bf16 -> 294912 fl
#define OFF_XT    442368    // xT  [9216][48] f32 -> 442368 fl
#define OFF_XTP   884736    // XTP [98*98][64] bf16 -> 307328 fl
#define OFF_WB    1192064   // WB  [16][48][64] bf16 -> 24576 fl
#define OFF_PART  1216640   // PART[288][16][2048] bf16 -> 4718592 fl
#define WS_NEED_BYTES ((size_t)5935232 * 4)

typedef __attribute__((ext_vector_type(4))) short s16x4;
typedef __attribute__((ext_vector_type(8))) short s16x8;
typedef __attribute__((ext_vector_type(4))) float f32x4;

#if __has_builtin(__builtin_amdgcn_mfma_f32_16x16x16bf16_1k)
static __device__ inline f32x4 mfma16(s16x4 a, s16x4 b, f32x4 c) {
    return __builtin_amdgcn_mfma_f32_16x16x16bf16_1k(a, b, c, 0, 0, 0);
}
#else
static __device__ inline f32x4 mfma16(s16x4 a, s16x4 b, f32x4 c) {
    asm volatile("v_mfma_f32_16x16x16_bf16 %0, %1, %2, %0" : "+v"(c) : "v"(a), "v"(b));
    return c;
}
#endif

static __device__ inline f32x4 mfma32(s16x8 a, s16x8 b, f32x4 c) {
    return __builtin_amdgcn_mfma_f32_16x16x32_bf16(a, b, c, 0, 0, 0);
}

// raw v_exp_f32: computes 2^x (scores pre-scaled by log2e) — proven codegen R4/R8-R15
static __device__ inline float fexp2(float x) {
    float r;
    asm("v_exp_f32 %0, %1" : "=v"(r) : "v"(x));
    return r;
}

static __device__ inline unsigned short f2bf(float f) {
    union { float f; unsigned u; } v; v.f = f;
    unsigned r = v.u + 0x7fff + ((v.u >> 16) & 1);
    return (unsigned short)(r >> 16);
}

static __device__ inline float bf2f(unsigned short u) {
    union { unsigned u; float f; } v; v.u = ((unsigned)u) << 16; return v.f;
}

static __device__ inline s16x4 pack_bf16x4(float a, float b, float c, float d) {
    __hip_bfloat162 h0 = __float22bfloat162_rn(make_float2(a, b));
    __hip_bfloat162 h1 = __float22bfloat162_rn(make_float2(c, d));
    union { unsigned u[2]; s16x4 v; } pu;
    pu.u[0] = *reinterpret_cast<unsigned*>(&h0);
    pu.u[1] = *reinterpret_cast<unsigned*>(&h1);
    return pu.v;
}

// pool (blocks 0..1727) + WB prep + XTP halo zero (blocks 1728..1919) — R13-proven fusion
__global__ void pool_wprep_k(const float* __restrict__ in, float* __restrict__ xT,
                             const float* __restrict__ dw, unsigned short* __restrict__ WB,
                             unsigned short* __restrict__ XTP) {
    int b = blockIdx.x;
    if (b < 1728) {
        int idx = b * 256 + threadIdx.x;
        int c = idx / NP, r = idx % NP;
        int y = r / WP, xx = r % WP;
        const float* p = in + (size_t)c * HH * WW + (2 * y) * WW + 2 * xx;
        xT[(size_t)r * 48 + c] = 0.25f * (p[0] + p[1] + p[WW] + p[WW + 1]);
        return;
    }
    int idx = (b - 1728) * 256 + threadIdx.x;   // 0..49151
    if (idx < 3104) {   // 388 halo positions x 8 threads x 8 c
        int pos = idx >> 3, cc = (idx & 7) * 8;
        int row, col;
        if (pos < 98)       { row = 0;             col = pos; }
        else if (pos < 196) { row = 97;            col = pos - 98; }
        else if (pos < 292) { row = pos - 196 + 1; col = 0; }
        else                { row = pos - 292 + 1; col = 97; }
        s16x8 zz = (s16x8){0, 0, 0, 0, 0, 0, 0, 0};
        *(s16x8*)(XTP + ((size_t)row * 98 + col) * 64 + cc) = zz;
    }
    int ci = idx & 63;
    int co = (idx >> 6) % 48;
    int kidx = idx / (48 * 64);
    float v = (ci < C) ? dw[((size_t)ci * C + co) * 16 + kidx] : 0.f;
    WB[idx] = f2bf(v);
}

// 5-group prep: g0->QB, g1->KB(+VT2 pad rows), g2..4->VT2 v-rows
__global__ void qkvprep_k(const float* __restrict__ xT,
                          const float* __restrict__ qw, const float* __restrict__ qb,
                          const float* __restrict__ kw, const float* __restrict__ kb,
                          const float* __restrict__ vw, const float* __restrict__ vb,
                          unsigned short* __restrict__ QB, unsigned short* __restrict__ KB,
                          unsigned short* __restrict__ VT2) {
    int tid = blockIdx.x * 256 + threadIdx.x;   // 5*9216 threads
    int p = tid % NP;
    int g = tid / NP;
    float f[C];
#pragma unroll
    for (int c4 = 0; c4 < C; c4 += 4) {
        f32x4 v = *(const f32x4*)(xT + (size_t)p * 48 + c4);
        f[c4] = v[0]; f[c4 + 1] = v[1]; f[c4 + 2] = v[2]; f[c4 + 3] = v[3];
    }
    int nt = p >> 4, nn = p & 15;
    if (g == 0) {
#pragma unroll
        for (int o = 0; o < 16; ++o) {
            float a = qb[o];
#pragma unroll
            for (int c = 0; c < C; ++c) a += qw[o * C + c] * f[c];
            QB[p * 16 + o] = f2bf(a);
        }
    } else if (g == 1) {
        const float L2E = 1.4426950408889634f;
#pragma unroll
        for (int o = 0; o < 16; ++o) {
            float a = kb[o];
#pragma unroll
            for (int c = 0; c < C; ++c) a += kw[o * C + c] * f[c];
            KB[p * 16 + o] = f2bf(a * L2E);
        }
        VT2[(size_t)nt * 1024 + 48 * 16 + nn] = 0x3F80;  // row 48 = ones (den)
#pragma unroll
        for (int r = 49; r < 64; ++r) VT2[(size_t)nt * 1024 + r * 16 + nn] = 0;
    } else {
        int c0 = (g - 2) * 16;
#pragma unroll
        for (int oo = 0; oo < 16; ++oo) {
            int o = c0 + oo;
            float a = vb[o];
#pragma unroll
            for (int c = 0; c < C; ++c) a += vw[o * C + c] * f[c];
            VT2[(size_t)nt * 1024 + o * 16 + nn] = f2bf(a);
        }
    }
}

#define MBLKS 72
#define NSPL  16
#define NSTEP 36   // 576 n per wave / 16

// 2-deep software pipeline (R15-proven). Tail over-reads stay inside d_ws.
template<int STEPS>
static __device__ __forceinline__ void attn_core32(const unsigned short* __restrict__ QB,
                                                   const unsigned short* __restrict__ VT2,
                                                   s16x4 bq0, s16x4 bq1, int n0, int lo, int hi,
                                                   f32x4 o0[4], f32x4 o1[4]) {
    const unsigned short* qp = QB + (size_t)(n0 + lo) * 16 + 4 * hi;
    const unsigned short* vp = VT2 + (size_t)(n0 >> 4) * 1024 + lo * 16 + 4 * hi;
    s16x4 aqA  = *(const s16x4*)qp;
    s16x4 bvA0 = *(const s16x4*)(vp);
    s16x4 bvA1 = *(const s16x4*)(vp + 256);
    s16x4 bvA2 = *(const s16x4*)(vp + 512);
    s16x4 bvA3 = *(const s16x4*)(vp + 768);
    qp += 256; vp += 1024;
    s16x4 aqB  = *(const s16x4*)qp;
    s16x4 bvB0 = *(const s16x4*)(vp);
    s16x4 bvB1 = *(const s16x4*)(vp + 256);
    s16x4 bvB2 = *(const s16x4*)(vp + 512);
    s16x4 bvB3 = *(const s16x4*)(vp + 768);

    for (int s = 0; s < STEPS; ++s) {
        qp += 256; vp += 1024;
        s16x4 aqn  = *(const s16x4*)qp;
        s16x4 bvn0 = *(const s16x4*)(vp);
        s16x4 bvn1 = *(const s16x4*)(vp + 256);
        s16x4 bvn2 = *(const s16x4*)(vp + 512);
        s16x4 bvn3 = *(const s16x4*)(vp + 768);

        f32x4 z = {0.f, 0.f, 0.f, 0.f};
        f32x4 t0 = mfma16(aqA, bq0, z);
        f32x4 t1 = mfma16(aqA, bq1, z);
        s16x4 p0 = pack_bf16x4(fexp2(t0[0]), fexp2(t0[1]), fexp2(t0[2]), fexp2(t0[3]));
        s16x4 p1 = pack_bf16x4(fexp2(t1[0]), fexp2(t1[1]), fexp2(t1[2]), fexp2(t1[3]));
        o0[0] = mfma16(p0, bvA0, o0[0]);
        o0[1] = mfma16(p0, bvA1, o0[1]);
        o0[2] = mfma16(p0, bvA2, o0[2]);
        o0[3] = mfma16(p0, bvA3, o0[3]);
        o1[0] = mfma16(p1, bvA0, o1[0]);
        o1[1] = mfma16(p1, bvA1, o1[1]);
        o1[2] = mfma16(p1, bvA2, o1[2]);
        o1[3] = mfma16(p1, bvA3, o1[3]);

        aqA = aqB; bvA0 = bvB0; bvA1 = bvB1; bvA2 = bvB2; bvA3 = bvB3;
        aqB = aqn; bvB0 = bvn0; bvB1 = bvn1; bvB2 = bvn2; bvB3 = bvn3;
    }
}

// Atomic-free attn: 32m per wave, NSPL=16 (1152 blocks). launch_bounds(256,2) — R15-proven.
__global__ __launch_bounds__(256, 2) void attn_k(const unsigned short* __restrict__ QB,
                                                 const unsigned short* __restrict__ KB,
                                                 const unsigned short* __restrict__ VT2,
                                                 unsigned short* __restrict__ PART) {
    const int lane = threadIdx.x & 63;
    const int lo = lane & 15, hi = lane >> 4;
    const int wv = threadIdx.x >> 6;
    const int mblk = blockIdx.x % MBLKS;
    const int nspl = blockIdx.x / MBLKS;
    const int mt0 = mblk * 128 + wv * 32;

    const s16x4 bq0 = *(const s16x4*)(KB + (size_t)(mt0 + lo) * 16 + 4 * hi);
    const s16x4 bq1 = *(const s16x4*)(KB + (size_t)(mt0 + 16 + lo) * 16 + 4 * hi);

    f32x4 o0[4], o1[4];
#pragma unroll
    for (int i = 0; i < 4; ++i) {
        o0[i] = (f32x4){0.f, 0.f, 0.f, 0.f};
        o1[i] = (f32x4){0.f, 0.f, 0.f, 0.f};
    }
    attn_core32<NSTEP>(QB, VT2, bq0, bq1, nspl * (NP / NSPL), lo, hi, o0, o1);

    unsigned short* cp = PART + ((size_t)(mblk * 4 + wv) * NSPL + nspl) * 2048;
#pragma unroll
    for (int q = 0; q < 8; ++q) {
        const f32x4& o = (q >> 2) ? o1[q & 3] : o0[q & 3];
        s16x4 pk = pack_bf16x4(o[0], o[1], o[2], o[3]);
        *(s16x4*)(cp + q * 256 + lane * 4) = pk;
    }
}

// Reduce 16 chunks + epilogue. One block per 32-m tile (288 blocks).
__global__ __launch_bounds__(256) void reduce_epi_k(const unsigned short* __restrict__ PART,
                                                    const float* __restrict__ xT,
                                                    const float* __restrict__ gamma,
                                                    unsigned short* __restrict__ XTP) {
    __shared__ float sden[32];
    const int T = blockIdx.x;          // 288 tiles
    const int mt0 = (T >> 2) * 128 + (T & 3) * 32;
    const unsigned short* base = PART + (size_t)T * NSPL * 2048;
    const int t = threadIdx.x;

    if (t < 8) {   // den: c=48 -> ct=3, lo=0; groups (h,hi)
        int h = t >> 2, hi = t & 3;
        int idx = (h * 4 + 3) * 256 + (hi * 16) * 4;
        float a0 = 0.f, a1 = 0.f, a2 = 0.f, a3 = 0.f;
        for (int ns = 0; ns < NSPL; ++ns) {
            s16x4 v = *(const s16x4*)(base + ns * 2048 + idx);
            a0 += bf2f((unsigned short)v[0]);
            a1 += bf2f((unsigned short)v[1]);
            a2 += bf2f((unsigned short)v[2]);
            a3 += bf2f((unsigned short)v[3]);
        }
        sden[h * 16 + hi * 4 + 0] = a0;
        sden[h * 16 + hi * 4 + 1] = a1;
        sden[h * 16 + hi * 4 + 2] = a2;
        sden[h * 16 + hi * 4 + 3] = a3;
    }
    __syncthreads();

    float gam = gamma[0];
#pragma unroll
    for (int g = t; g < 512; g += 256) {
        int q = g >> 6, lane = g & 63;
        int h = q >> 2, ct = q & 3;
        int hi = lane >> 4, lo = lane & 15;
        int c = ct * 16 + lo;
        int idx = q * 256 + lane * 4;
        float a0 = 0.f, a1 = 0.f, a2 = 0.f, a3 = 0.f;
        for (int ns = 0; ns < NSPL; ++ns) {
            s16x4 v = *(const s16x4*)(base + ns * 2048 + idx);
            a0 += bf2f((unsigned short)v[0]);
            a1 += bf2f((unsigned short)v[1]);
            a2 += bf2f((unsigned short)v[2]);
            a3 += bf2f((unsigned short)v[3]);
        }
        if (c < 48) {
            float av[4] = {a0, a1, a2, a3};
#pragma unroll
            for (int j = 0; j < 4; ++j) {
                int ml = h * 16 + hi * 4 + j;
                int m = mt0 + ml;
                float val = gam * av[j] / sden[ml] + xT[(size_t)m * 48 + c];
                int iy = m / WP, ix = m % WP;
                XTP[((size_t)(iy + 1) * 98 + ix + 1) * 64 + c] = f2bf(val);
            }
        }
    }
}

// ---------- fallback path (small ws): atomics into O4 (overlays PART) ----------
__global__ __launch_bounds__(256) void attn_atomic_k(const unsigned short* __restrict__ QB,
                                                     const unsigned short* __restrict__ KB,
                                                     const unsigned short* __restrict__ VT2,
                                                     float* __restrict__ O4) {
    const int lane = threadIdx.x & 63;
    const int lo = lane & 15, hi = lane >> 4;
    const int wv = threadIdx.x >> 6;
    const int mblk = blockIdx.x % 72;
    const int nspl = blockIdx.x / 72;
    const int mt0 = mblk * 128 + wv * 32;
    const s16x4 bq0 = *(const s16x4*)(KB + (size_t)(mt0 + lo) * 16 + 4 * hi);
    const s16x4 bq1 = *(const s16x4*)(KB + (size_t)(mt0 + 16 + lo) * 16 + 4 * hi);
    f32x4 o0[4], o1[4];
#pragma unroll
    for (int i = 0; i < 4; ++i) {
        o0[i] = (f32x4){0.f, 0.f, 0.f, 0.f};
        o1[i] = (f32x4){0.f, 0.f, 0.f, 0.f};
    }
    attn_core32<18>(QB, VT2, bq0, bq1, nspl * 288, lo, hi, o0, o1);
    float* Oc = O4 + (size_t)(nspl & 3) * (NP * 64);
#pragma unroll
    for (int ct = 0; ct < 4; ++ct)
#pragma unroll
        for (int j = 0; j < 4; ++j) {
            atomicAdd(&Oc[(size_t)(mt0 + 4 * hi + j) * 64 + 16 * ct + lo], o0[ct][j]);
            atomicAdd(&Oc[(size_t)(mt0 + 16 + 4 * hi + j) * 64 + 16 * ct + lo], o1[ct][j]);
        }
}

__global__ void epi_atomic_k(const float* __restrict__ O4, const float* __restrict__ xT,
                             const float* __restrict__ gamma, unsigned short* __restrict__ XTP) {
    int m = blockIdx.x * 256 + threadIdx.x;
    if (m >= NP) return;
    int iy = m / WP, ix = m % WP;
    unsigned short* xp = XTP + ((size_t)(iy + 1) * 98 + ix + 1) * 64;
    float den = 0.f;
#pragma unroll
    for (int cp = 0; cp < 4; ++cp) den += O4[(size_t)cp * (NP * 64) + (size_t)m * 64 + 48];
    float rg = gamma[0] / den;
#pragma unroll
    for (int c = 0; c < C; ++c) {
        float o = 0.f;
#pragma unroll
        for (int cp = 0; cp < 4; ++cp) o += O4[(size_t)cp * (NP * 64) + (size_t)m * 64 + c];
        xp[c] = f2bf(rg * o + xT[(size_t)m * 48 + c]);
    }
}

// ConvTranspose2d via MFMA; one 16-ox tile per wave (1152 blocks).
__global__ __launch_bounds__(128) void convt_mfma_k(const unsigned short* __restrict__ XTP,
                                                    const unsigned short* __restrict__ WB,
                                                    const float* __restrict__ db,
                                                    float* __restrict__ y) {
    const int lane = threadIdx.x & 63;
    const int lo = lane & 15, hi = lane >> 4;
    const int wv = threadIdx.x >> 6;   // 0..1
    const int b = blockIdx.x;          // 96*2*2*3
    const int i3 = b % 3;
    const int r3 = b / 3;
    const int px = r3 & 1;
    const int py = (r3 >> 1) & 1;
    const int oyp = r3 >> 2;

    const int sy[2] = {0, py ? 1 : -1};
    const int kyt[2] = {py ? 2 : 1, py ? 0 : 3};
    const int sx[2] = {0, px ? 1 : -1};
    const int kxt[2] = {px ? 2 : 1, px ? 0 : 3};

    s16x8 bw[2][2][2][3];  // [ty][tx][kk][ct]
#pragma unroll
    for (int ty = 0; ty < 2; ++ty)
#pragma unroll
        for (int tx = 0; tx < 2; ++tx) {
            const unsigned short* wp = WB + (size_t)(kyt[ty] * 4 + kxt[tx]) * 48 * 64;
#pragma unroll
            for (int kk = 0; kk < 2; ++kk)
#pragma unroll
                for (int ct = 0; ct < 3; ++ct)
                    bw[ty][tx][kk][ct] = *(const s16x8*)(wp + (size_t)(ct * 16 + lo) * 64 + kk * 32 + 8 * hi);
        }
    float bias[3];
#pragma unroll
    for (int ct = 0; ct < 3; ++ct) bias[ct] = db[ct * 16 + lo];

    const int oy = 2 * oyp + py;
    const int ox0 = (wv * 3 + i3) * 16;
    f32x4 acc[3];
#pragma unroll
    for (int ct = 0; ct < 3; ++ct) acc[ct] = (f32x4){bias[ct], bias[ct], bias[ct], bias[ct]};
#pragma unroll
    for (int ty = 0; ty < 2; ++ty) {
        int R0 = (oyp + sy[ty] + 1) * 98;
#pragma unroll
        for (int tx = 0; tx < 2; ++tx) {
            const unsigned short* ap = XTP + (size_t)(R0 + ox0 + sx[tx] + 1 + lo) * 64 + 8 * hi;
#pragma unroll
            for (int kk = 0; kk < 2; ++kk) {
                s16x8 a = *(const s16x8*)(ap + kk * 32);
                acc[0] = mfma32(a, bw[ty][tx][kk][0], acc[0]);
                acc[1] = mfma32(a, bw[ty][tx][kk][1], acc[1]);
                acc[2] = mfma32(a, bw[ty][tx][kk][2], acc[2]);
            }
        }
    }
#pragma unroll
    for (int ct = 0; ct < 3; ++ct)
#pragma unroll
        for (int j = 0; j < 4; ++j)
            y[(size_t)(ct * 16 + lo) * (HH * WW) + oy * WW + 2 * (ox0 + 4 * hi + j) + px] = acc[ct][j];
}

extern "C" void kernel_launch(void* const* d_in, const int* in_sizes, int n_in,
                              void* d_out, int out_size, void* d_ws, size_t ws_size,
                              hipStream_t stream) {
    const float* in    = (const float*)d_in[0];
    const float* qw    = (const float*)d_in[1];
    const float* qb    = (const float*)d_in[2];
    const float* kw    = (const float*)d_in[3];
    const float* kb    = (const float*)d_in[4];
    const float* vw    = (const float*)d_in[5];
    const float* vb    = (const float*)d_in[6];
    const float* gamma = (const float*)d_in[7];
    const float* dw    = (const float*)d_in[8];
    const float* db    = (const float*)d_in[9];
    float* out = (float*)d_out;

    float* ws = (float*)d_ws;
    unsigned short* QB   = (unsigned short*)(ws + OFF_QB);
    unsigned short* KB   = (unsigned short*)(ws + OFF_KB);
    unsigned short* VT2  = (unsigned short*)(ws + OFF_VT2);
    float*          xT   = ws + OFF_XT;
    unsigned short* XTP  = (unsigned short*)(ws + OFF_XTP);
    unsigned short* WB   = (unsigned short*)(ws + OFF_WB);
    unsigned short* PART = (unsigned short*)(ws + OFF_PART);

    pool_wprep_k<<<1920, 256, 0, stream>>>(in, xT, dw, WB, XTP);
    qkvprep_k<<<(5 * NP) / 256, 256, 0, stream>>>(xT, qw, qb, kw, kb, vw, vb, QB, KB, VT2);

    if (ws_size >= WS_NEED_BYTES) {
        attn_k<<<MBLKS * NSPL, 256, 0, stream>>>(QB, KB, VT2, PART);
        reduce_epi_k<<<288, 256, 0, stream>>>(PART, xT, gamma, XTP);
    } else {
        float* O4 = (float*)PART;   // overlays PART region
        hipMemsetAsync(O4, 0, (size_t)4 * NP * 64 * sizeof(float), stream);
        attn_atomic_k<<<72 * 32, 256, 0, stream>>>(QB, KB, VT2, O4);
        epi_atomic_k<<<(NP + 255) / 256, 256, 0, stream>>>(O4, xT, gamma, XTP);
    }
    convt_mfma_k<<<96 * 2 * 2 * 3, 128, 0, stream>>>(XTP, WB, db, out);
}

// Round 18
// 82.105 us; speedup vs baseline: 1.1075x; 1.0102x over previous
//
#include <hip/hip_runtime.h>
#include <hip/hip_bf16.h>

#define C 48
#define HH 192
#define WW 192
#define HP 96
#define WP 96
#define NP 9216   // 96*96

// ws layout (float offsets) — checked sizes (R15/R17-proven)
#define OFF_QB    0         // QB  [9216][16] bf16  -> 73728 fl
#define OFF_KB    73728     // KB  [9216][16] bf16  -> 73728 fl
#define OFF_VT2   147456    // VT2 [576][64][16] bf16 -> 294912 fl
#define OFF_XT    442368    // xT  [9216][48] f32 -> 442368 fl
#define OFF_XTP   884736    // XTP [98*98][64] bf16 -> 307328 fl
#define OFF_WB    1192064   // WB  [16][48][64] bf16 -> 24576 fl
#define OFF_PART  1216640   // PART[288][16][2048] bf16 -> 4718592 fl
#define WS_NEED_BYTES ((size_t)5935232 * 4)

typedef __attribute__((ext_vector_type(4))) short s16x4;
typedef __attribute__((ext_vector_type(8))) short s16x8;
typedef __attribute__((ext_vector_type(4))) float f32x4;

#if __has_builtin(__builtin_amdgcn_mfma_f32_16x16x16bf16_1k)
static __device__ inline f32x4 mfma16(s16x4 a, s16x4 b, f32x4 c) {
    return __builtin_amdgcn_mfma_f32_16x16x16bf16_1k(a, b, c, 0, 0, 0);
}
#else
static __device__ inline f32x4 mfma16(s16x4 a, s16x4 b, f32x4 c) {
    asm volatile("v_mfma_f32_16x16x16_bf16 %0, %1, %2, %0" : "+v"(c) : "v"(a), "v"(b));
    return c;
}
#endif

static __device__ inline f32x4 mfma32(s16x8 a, s16x8 b, f32x4 c) {
    return __builtin_amdgcn_mfma_f32_16x16x32_bf16(a, b, c, 0, 0, 0);
}

// raw v_exp_f32: computes 2^x (scores pre-scaled by log2e) — proven codegen R4/R8-R17
static __device__ inline float fexp2(float x) {
    float r;
    asm("v_exp_f32 %0, %1" : "=v"(r) : "v"(x));
    return r;
}

static __device__ inline unsigned short f2bf(float f) {
    union { float f; unsigned u; } v; v.f = f;
    unsigned r = v.u + 0x7fff + ((v.u >> 16) & 1);
    return (unsigned short)(r >> 16);
}

static __device__ inline float bf2f(unsigned short u) {
    union { unsigned u; float f; } v; v.u = ((unsigned)u) << 16; return v.f;
}

static __device__ inline s16x4 pack_bf16x4(float a, float b, float c, float d) {
    __hip_bfloat162 h0 = __float22bfloat162_rn(make_float2(a, b));
    __hip_bfloat162 h1 = __float22bfloat162_rn(make_float2(c, d));
    union { unsigned u[2]; s16x4 v; } pu;
    pu.u[0] = *reinterpret_cast<unsigned*>(&h0);
    pu.u[1] = *reinterpret_cast<unsigned*>(&h1);
    return pu.v;
}

// pool (blocks 0..1727) + WB prep + XTP halo zero (blocks 1728..1919) — R13/R17-proven fusion
__global__ void pool_wprep_k(const float* __restrict__ in, float* __restrict__ xT,
                             const float* __restrict__ dw, unsigned short* __restrict__ WB,
                             unsigned short* __restrict__ XTP) {
    int b = blockIdx.x;
    if (b < 1728) {
        int idx = b * 256 + threadIdx.x;
        int c = idx / NP, r = idx % NP;
        int y = r / WP, xx = r % WP;
        const float* p = in + (size_t)c * HH * WW + (2 * y) * WW + 2 * xx;
        xT[(size_t)r * 48 + c] = 0.25f * (p[0] + p[1] + p[WW] + p[WW + 1]);
        return;
    }
    int idx = (b - 1728) * 256 + threadIdx.x;   // 0..49151
    if (idx < 3104) {   // 388 halo positions x 8 threads x 8 c
        int pos = idx >> 3, cc = (idx & 7) * 8;
        int row, col;
        if (pos < 98)       { row = 0;             col = pos; }
        else if (pos < 196) { row = 97;            col = pos - 98; }
        else if (pos < 292) { row = pos - 196 + 1; col = 0; }
        else                { row = pos - 292 + 1; col = 97; }
        s16x8 zz = (s16x8){0, 0, 0, 0, 0, 0, 0, 0};
        *(s16x8*)(XTP + ((size_t)row * 98 + col) * 64 + cc) = zz;
    }
    int ci = idx & 63;
    int co = (idx >> 6) % 48;
    int kidx = idx / (48 * 64);
    float v = (ci < C) ? dw[((size_t)ci * C + co) * 16 + kidx] : 0.f;
    WB[idx] = f2bf(v);
}

// 5-group prep: g0->QB, g1->KB(+VT2 pad rows), g2..4->VT2 v-rows
__global__ void qkvprep_k(const float* __restrict__ xT,
                          const float* __restrict__ qw, const float* __restrict__ qb,
                          const float* __restrict__ kw, const float* __restrict__ kb,
                          const float* __restrict__ vw, const float* __restrict__ vb,
                          unsigned short* __restrict__ QB, unsigned short* __restrict__ KB,
                          unsigned short* __restrict__ VT2) {
    int tid = blockIdx.x * 256 + threadIdx.x;   // 5*9216 threads
    int p = tid % NP;
    int g = tid / NP;
    float f[C];
#pragma unroll
    for (int c4 = 0; c4 < C; c4 += 4) {
        f32x4 v = *(const f32x4*)(xT + (size_t)p * 48 + c4);
        f[c4] = v[0]; f[c4 + 1] = v[1]; f[c4 + 2] = v[2]; f[c4 + 3] = v[3];
    }
    int nt = p >> 4, nn = p & 15;
    if (g == 0) {
#pragma unroll
        for (int o = 0; o < 16; ++o) {
            float a = qb[o];
#pragma unroll
            for (int c = 0; c < C; ++c) a += qw[o * C + c] * f[c];
            QB[p * 16 + o] = f2bf(a);
        }
    } else if (g == 1) {
        const float L2E = 1.4426950408889634f;
#pragma unroll
        for (int o = 0; o < 16; ++o) {
            float a = kb[o];
#pragma unroll
            for (int c = 0; c < C; ++c) a += kw[o * C + c] * f[c];
            KB[p * 16 + o] = f2bf(a * L2E);
        }
        VT2[(size_t)nt * 1024 + 48 * 16 + nn] = 0x3F80;  // row 48 = ones (den)
#pragma unroll
        for (int r = 49; r < 64; ++r) VT2[(size_t)nt * 1024 + r * 16 + nn] = 0;
    } else {
        int c0 = (g - 2) * 16;
#pragma unroll
        for (int oo = 0; oo < 16; ++oo) {
            int o = c0 + oo;
            float a = vb[o];
#pragma unroll
            for (int c = 0; c < C; ++c) a += vw[o * C + c] * f[c];
            VT2[(size_t)nt * 1024 + o * 16 + nn] = f2bf(a);
        }
    }
}

#define MBLKS 72
#define NSPL  16
#define NSTEP 36   // 576 n per wave / 16

// 2-deep software pipeline (R15/R17-proven). Tail over-reads stay inside d_ws.
template<int STEPS>
static __device__ __forceinline__ void attn_core32(const unsigned short* __restrict__ QB,
                                                   const unsigned short* __restrict__ VT2,
                                                   s16x4 bq0, s16x4 bq1, int n0, int lo, int hi,
                                                   f32x4 o0[4], f32x4 o1[4]) {
    const unsigned short* qp = QB + (size_t)(n0 + lo) * 16 + 4 * hi;
    const unsigned short* vp = VT2 + (size_t)(n0 >> 4) * 1024 + lo * 16 + 4 * hi;
    s16x4 aqA  = *(const s16x4*)qp;
    s16x4 bvA0 = *(const s16x4*)(vp);
    s16x4 bvA1 = *(const s16x4*)(vp + 256);
    s16x4 bvA2 = *(const s16x4*)(vp + 512);
    s16x4 bvA3 = *(const s16x4*)(vp + 768);
    qp += 256; vp += 1024;
    s16x4 aqB  = *(const s16x4*)qp;
    s16x4 bvB0 = *(const s16x4*)(vp);
    s16x4 bvB1 = *(const s16x4*)(vp + 256);
    s16x4 bvB2 = *(const s16x4*)(vp + 512);
    s16x4 bvB3 = *(const s16x4*)(vp + 768);

    for (int s = 0; s < STEPS; ++s) {
        qp += 256; vp += 1024;
        s16x4 aqn  = *(const s16x4*)qp;
        s16x4 bvn0 = *(const s16x4*)(vp);
        s16x4 bvn1 = *(const s16x4*)(vp + 256);
        s16x4 bvn2 = *(const s16x4*)(vp + 512);
        s16x4 bvn3 = *(const s16x4*)(vp + 768);

        f32x4 z = {0.f, 0.f, 0.f, 0.f};
        f32x4 t0 = mfma16(aqA, bq0, z);
        f32x4 t1 = mfma16(aqA, bq1, z);
        s16x4 p0 = pack_bf16x4(fexp2(t0[0]), fexp2(t0[1]), fexp2(t0[2]), fexp2(t0[3]));
        s16x4 p1 = pack_bf16x4(fexp2(t1[0]), fexp2(t1[1]), fexp2(t1[2]), fexp2(t1[3]));
        o0[0] = mfma16(p0, bvA0, o0[0]);
        o0[1] = mfma16(p0, bvA1, o0[1]);
        o0[2] = mfma16(p0, bvA2, o0[2]);
        o0[3] = mfma16(p0, bvA3, o0[3]);
        o1[0] = mfma16(p1, bvA0, o1[0]);
        o1[1] = mfma16(p1, bvA1, o1[1]);
        o1[2] = mfma16(p1, bvA2, o1[2]);
        o1[3] = mfma16(p1, bvA3, o1[3]);

        aqA = aqB; bvA0 = bvB0; bvA1 = bvB1; bvA2 = bvB2; bvA3 = bvB3;
        aqB = aqn; bvB0 = bvn0; bvB1 = bvn1; bvB2 = bvn2; bvB3 = bvn3;
    }
}

// Atomic-free attn: 32m per wave, NSPL=16 (1152 blocks). launch_bounds(256,2) — FROZEN.
__global__ __launch_bounds__(256, 2) void attn_k(const unsigned short* __restrict__ QB,
                                                 const unsigned short* __restrict__ KB,
                                                 const unsigned short* __restrict__ VT2,
                                                 unsigned short* __restrict__ PART) {
    const int lane = threadIdx.x & 63;
    const int lo = lane & 15, hi = lane >> 4;
    const int wv = threadIdx.x >> 6;
    const int mblk = blockIdx.x % MBLKS;
    const int nspl = blockIdx.x / MBLKS;
    const int mt0 = mblk * 128 + wv * 32;

    const s16x4 bq0 = *(const s16x4*)(KB + (size_t)(mt0 + lo) * 16 + 4 * hi);
    const s16x4 bq1 = *(const s16x4*)(KB + (size_t)(mt0 + 16 + lo) * 16 + 4 * hi);

    f32x4 o0[4], o1[4];
#pragma unroll
    for (int i = 0; i < 4; ++i) {
        o0[i] = (f32x4){0.f, 0.f, 0.f, 0.f};
        o1[i] = (f32x4){0.f, 0.f, 0.f, 0.f};
    }
    attn_core32<NSTEP>(QB, VT2, bq0, bq1, nspl * (NP / NSPL), lo, hi, o0, o1);

    unsigned short* cp = PART + ((size_t)(mblk * 4 + wv) * NSPL + nspl) * 2048;
#pragma unroll
    for (int q = 0; q < 8; ++q) {
        const f32x4& o = (q >> 2) ? o1[q & 3] : o0[q & 3];
        s16x4 pk = pack_bf16x4(o[0], o[1], o[2], o[3]);
        *(s16x4*)(cp + q * 256 + lane * 4) = pk;
    }
}

// Reduce 16 chunks + epilogue. 576 blocks = 288 tiles x 2 halves (R12-proven split).
__global__ __launch_bounds__(256) void reduce_epi_k(const unsigned short* __restrict__ PART,
                                                    const float* __restrict__ xT,
                                                    const float* __restrict__ gamma,
                                                    unsigned short* __restrict__ XTP) {
    __shared__ float sden[32];
    const int B = blockIdx.x;
    const int T = B >> 1, half = B & 1;
    const int mt0 = (T >> 2) * 128 + (T & 3) * 32;
    const unsigned short* base = PART + (size_t)T * NSPL * 2048;
    const int t = threadIdx.x;

    if (t < 8) {   // den: c=48 -> ct=3, lo=0; groups (h,hi)
        int h = t >> 2, hi = t & 3;
        int idx = (h * 4 + 3) * 256 + (hi * 16) * 4;
        float a0 = 0.f, a1 = 0.f, a2 = 0.f, a3 = 0.f;
        for (int ns = 0; ns < NSPL; ++ns) {
            s16x4 v = *(const s16x4*)(base + ns * 2048 + idx);
            a0 += bf2f((unsigned short)v[0]);
            a1 += bf2f((unsigned short)v[1]);
            a2 += bf2f((unsigned short)v[2]);
            a3 += bf2f((unsigned short)v[3]);
        }
        sden[h * 16 + hi * 4 + 0] = a0;
        sden[h * 16 + hi * 4 + 1] = a1;
        sden[h * 16 + hi * 4 + 2] = a2;
        sden[h * 16 + hi * 4 + 3] = a3;
    }
    __syncthreads();

    float gam = gamma[0];
    int g = half * 256 + t;
    int q = g >> 6, lane = g & 63;
    int h = q >> 2, ct = q & 3;
    int hi = lane >> 4, lo = lane & 15;
    int c = ct * 16 + lo;
    int idx = q * 256 + lane * 4;
    float a0 = 0.f, a1 = 0.f, a2 = 0.f, a3 = 0.f;
    for (int ns = 0; ns < NSPL; ++ns) {
        s16x4 v = *(const s16x4*)(base + ns * 2048 + idx);
        a0 += bf2f((unsigned short)v[0]);
        a1 += bf2f((unsigned short)v[1]);
        a2 += bf2f((unsigned short)v[2]);
        a3 += bf2f((unsigned short)v[3]);
    }
    if (c < 48) {
        float av[4] = {a0, a1, a2, a3};
#pragma unroll
        for (int j = 0; j < 4; ++j) {
            int ml = h * 16 + hi * 4 + j;
            int m = mt0 + ml;
            float val = gam * av[j] / sden[ml] + xT[(size_t)m * 48 + c];
            int iy = m / WP, ix = m % WP;
            XTP[((size_t)(iy + 1) * 98 + ix + 1) * 64 + c] = f2bf(val);
        }
    }
}

// ---------- fallback path (small ws): atomics into O4 (overlays PART) ----------
__global__ __launch_bounds__(256) void attn_atomic_k(const unsigned short* __restrict__ QB,
                                                     const unsigned short* __restrict__ KB,
                                                     const unsigned short* __restrict__ VT2,
                                                     float* __restrict__ O4) {
    const int lane = threadIdx.x & 63;
    const int lo = lane & 15, hi = lane >> 4;
    const int wv = threadIdx.x >> 6;
    const int mblk = blockIdx.x % 72;
    const int nspl = blockIdx.x / 72;
    const int mt0 = mblk * 128 + wv * 32;
    const s16x4 bq0 = *(const s16x4*)(KB + (size_t)(mt0 + lo) * 16 + 4 * hi);
    const s16x4 bq1 = *(const s16x4*)(KB + (size_t)(mt0 + 16 + lo) * 16 + 4 * hi);
    f32x4 o0[4], o1[4];
#pragma unroll
    for (int i = 0; i < 4; ++i) {
        o0[i] = (f32x4){0.f, 0.f, 0.f, 0.f};
        o1[i] = (f32x4){0.f, 0.f, 0.f, 0.f};
    }
    attn_core32<18>(QB, VT2, bq0, bq1, nspl * 288, lo, hi, o0, o1);
    float* Oc = O4 + (size_t)(nspl & 3) * (NP * 64);
#pragma unroll
    for (int ct = 0; ct < 4; ++ct)
#pragma unroll
        for (int j = 0; j < 4; ++j) {
            atomicAdd(&Oc[(size_t)(mt0 + 4 * hi + j) * 64 + 16 * ct + lo], o0[ct][j]);
            atomicAdd(&Oc[(size_t)(mt0 + 16 + 4 * hi + j) * 64 + 16 * ct + lo], o1[ct][j]);
        }
}

__global__ void epi_atomic_k(const float* __restrict__ O4, const float* __restrict__ xT,
                             const float* __restrict__ gamma, unsigned short* __restrict__ XTP) {
    int m = blockIdx.x * 256 + threadIdx.x;
    if (m >= NP) return;
    int iy = m / WP, ix = m % WP;
    unsigned short* xp = XTP + ((size_t)(iy + 1) * 98 + ix + 1) * 64;
    float den = 0.f;
#pragma unroll
    for (int cp = 0; cp < 4; ++cp) den += O4[(size_t)cp * (NP * 64) + (size_t)m * 64 + 48];
    float rg = gamma[0] / den;
#pragma unroll
    for (int c = 0; c < C; ++c) {
        float o = 0.f;
#pragma unroll
        for (int cp = 0; cp < 4; ++cp) o += O4[(size_t)cp * (NP * 64) + (size_t)m * 64 + c];
        xp[c] = f2bf(rg * o + xT[(size_t)m * 48 + c]);
    }
}

// ConvTranspose2d via MFMA; one 16-ox tile per wave (1152 blocks).
__global__ __launch_bounds__(128) void convt_mfma_k(const unsigned short* __restrict__ XTP,
                                                    const unsigned short* __restrict__ WB,
                                                    const float* __restrict__ db,
                                                    float* __restrict__ y) {
    const int lane = threadIdx.x & 63;
    const int lo = lane & 15, hi = lane >> 4;
    const int wv = threadIdx.x >> 6;   // 0..1
    const int b = blockIdx.x;          // 96*2*2*3
    const int i3 = b % 3;
    const int r3 = b / 3;
    const int px = r3 & 1;
    const int py = (r3 >> 1) & 1;
    const int oyp = r3 >> 2;

    const int sy[2] = {0, py ? 1 : -1};
    const int kyt[2] = {py ? 2 : 1, py ? 0 : 3};
    const int sx[2] = {0, px ? 1 : -1};
    const int kxt[2] = {px ? 2 : 1, px ? 0 : 3};

    s16x8 bw[2][2][2][3];  // [ty][tx][kk][ct]
#pragma unroll
    for (int ty = 0; ty < 2; ++ty)
#pragma unroll
        for (int tx = 0; tx < 2; ++tx) {
            const unsigned short* wp = WB + (size_t)(kyt[ty] * 4 + kxt[tx]) * 48 * 64;
#pragma unroll
            for (int kk = 0; kk < 2; ++kk)
#pragma unroll
                for (int ct = 0; ct < 3; ++ct)
                    bw[ty][tx][kk][ct] = *(const s16x8*)(wp + (size_t)(ct * 16 + lo) * 64 + kk * 32 + 8 * hi);
        }
    float bias[3];
#pragma unroll
    for (int ct = 0; ct < 3; ++ct) bias[ct] = db[ct * 16 + lo];

    const int oy = 2 * oyp + py;
    const int ox0 = (wv * 3 + i3) * 16;
    f32x4 acc[3];
#pragma unroll
    for (int ct = 0; ct < 3; ++ct) acc[ct] = (f32x4){bias[ct], bias[ct], bias[ct], bias[ct]};
#pragma unroll
    for (int ty = 0; ty < 2; ++ty) {
        int R0 = (oyp + sy[ty] + 1) * 98;
#pragma unroll
        for (int tx = 0; tx < 2; ++tx) {
            const unsigned short* ap = XTP + (size_t)(R0 + ox0 + sx[tx] + 1 + lo) * 64 + 8 * hi;
#pragma unroll
            for (int kk = 0; kk < 2; ++kk) {
                s16x8 a = *(const s16x8*)(ap + kk * 32);
                acc[0] = mfma32(a, bw[ty][tx][kk][0], acc[0]);
                acc[1] = mfma32(a, bw[ty][tx][kk][1], acc[1]);
                acc[2] = mfma32(a, bw[ty][tx][kk][2], acc[2]);
            }
        }
    }
#pragma unroll
    for (int ct = 0; ct < 3; ++ct)
#pragma unroll
        for (int j = 0; j < 4; ++j)
            y[(size_t)(ct * 16 + lo) * (HH * WW) + oy * WW + 2 * (ox0 + 4 * hi + j) + px] = acc[ct][j];
}

extern "C" void kernel_launch(void* const* d_in, const int* in_sizes, int n_in,
                              void* d_out, int out_size, void* d_ws, size_t ws_size,
                              hipStream_t stream) {
    const float* in    = (const float*)d_in[0];
    const float* qw    = (const float*)d_in[1];
    const float* qb    = (const float*)d_in[2];
    const float* kw    = (const float*)d_in[3];
    const float* kb    = (const float*)d_in[4];
    const float* vw    = (const float*)d_in[5];
    const float* vb    = (const float*)d_in[6];
    const float* gamma = (const float*)d_in[7];
    const float* dw    = (const float*)d_in[8];
    const float* db    = (const float*)d_in[9];
    float* out = (float*)d_out;

    float* ws = (float*)d_ws;
    unsigned short* QB   = (unsigned short*)(ws + OFF_QB);
    unsigned short* KB   = (unsigned short*)(ws + OFF_KB);
    unsigned short* VT2  = (unsigned short*)(ws + OFF_VT2);
    float*          xT   = ws + OFF_XT;
    unsigned short* XTP  = (unsigned short*)(ws + OFF_XTP);
    unsigned short* WB   = (unsigned short*)(ws + OFF_WB);
    unsigned short* PART = (unsigned short*)(ws + OFF_PART);

    pool_wprep_k<<<1920, 256, 0, stream>>>(in, xT, dw, WB, XTP);
    qkvprep_k<<<(5 * NP) / 256, 256, 0, stream>>>(xT, qw, qb, kw, kb, vw, vb, QB, KB, VT2);

    if (ws_size >= WS_NEED_BYTES) {
        attn_k<<<MBLKS * NSPL, 256, 0, stream>>>(QB, KB, VT2, PART);
        reduce_epi_k<<<576, 256, 0, stream>>>(PART, xT, gamma, XTP);
    } else {
        float* O4 = (float*)PART;   // overlays PART region
        hipMemsetAsync(O4, 0, (size_t)4 * NP * 64 * sizeof(float), stream);
        attn_atomic_k<<<72 * 32, 256, 0, stream>>>(QB, KB, VT2, O4);
        epi_atomic_k<<<(NP + 255) / 256, 256, 0, stream>>>(O4, xT, gamma, XTP);
    }
    convt_mfma_k<<<96 * 2 * 2 * 3, 128, 0, stream>>>(XTP, WB, db, out);
}

// Round 19
// 80.753 us; speedup vs baseline: 1.1260x; 1.0167x over previous
//
#include <hip/hip_runtime.h>
#include <hip/hip_bf16.h>

#define C 48
#define HH 192
#define WW 192
#define HP 96
#define WP 96
#define NP 9216   // 96*96

// ws layout (float offsets) — checked sizes (R15/R17/R18-proven)
#define OFF_QB    0         // QB  [9216][16] bf16  -> 73728 fl
#define OFF_KB    73728     // KB  [9216][16] bf16  -> 73728 fl
#define OFF_VT2   147456    // VT2 [576][64][16] bf16 -> 294912 fl
#define OFF_XT    442368    // xT  [9216][48] f32 -> 442368 fl
#define OFF_XTP   884736    // XTP [98*98][64] bf16 -> 307328 fl
#define OFF_WB    1192064   // WB  [16][48][64] bf16 -> 24576 fl
#define OFF_PART  1216640   // PART[288][16][2048] bf16 -> 4718592 fl
#define WS_NEED_BYTES ((size_t)5935232 * 4)

typedef __attribute__((ext_vector_type(4))) short s16x4;
typedef __attribute__((ext_vector_type(8))) short s16x8;
typedef __attribute__((ext_vector_type(4))) float f32x4;

#if __has_builtin(__builtin_amdgcn_mfma_f32_16x16x16bf16_1k)
static __device__ inline f32x4 mfma16(s16x4 a, s16x4 b, f32x4 c) {
    return __builtin_amdgcn_mfma_f32_16x16x16bf16_1k(a, b, c, 0, 0, 0);
}
#else
static __device__ inline f32x4 mfma16(s16x4 a, s16x4 b, f32x4 c) {
    asm volatile("v_mfma_f32_16x16x16_bf16 %0, %1, %2, %0" : "+v"(c) : "v"(a), "v"(b));
    return c;
}
#endif

static __device__ inline f32x4 mfma32(s16x8 a, s16x8 b, f32x4 c) {
    return __builtin_amdgcn_mfma_f32_16x16x32_bf16(a, b, c, 0, 0, 0);
}

// raw v_exp_f32: computes 2^x (scores pre-scaled by log2e) — proven codegen R4/R8-R18
static __device__ inline float fexp2(float x) {
    float r;
    asm("v_exp_f32 %0, %1" : "=v"(r) : "v"(x));
    return r;
}

static __device__ inline unsigned short f2bf(float f) {
    union { float f; unsigned u; } v; v.f = f;
    unsigned r = v.u + 0x7fff + ((v.u >> 16) & 1);
    return (unsigned short)(r >> 16);
}

static __device__ inline float bf2f(unsigned short u) {
    union { unsigned u; float f; } v; v.u = ((unsigned)u) << 16; return v.f;
}

static __device__ inline s16x4 pack_bf16x4(float a, float b, float c, float d) {
    __hip_bfloat162 h0 = __float22bfloat162_rn(make_float2(a, b));
    __hip_bfloat162 h1 = __float22bfloat162_rn(make_float2(c, d));
    union { unsigned u[2]; s16x4 v; } pu;
    pu.u[0] = *reinterpret_cast<unsigned*>(&h0);
    pu.u[1] = *reinterpret_cast<unsigned*>(&h1);
    return pu.v;
}

// pool (blocks 0..1727) + WB prep + XTP halo zero (blocks 1728..1919)
__global__ void pool_wprep_k(const float* __restrict__ in, float* __restrict__ xT,
                             const float* __restrict__ dw, unsigned short* __restrict__ WB,
                             unsigned short* __restrict__ XTP) {
    int b = blockIdx.x;
    if (b < 1728) {
        int idx = b * 256 + threadIdx.x;
        int c = idx / NP, r = idx % NP;
        int y = r / WP, xx = r % WP;
        const float* p = in + (size_t)c * HH * WW + (2 * y) * WW + 2 * xx;
        xT[(size_t)r * 48 + c] = 0.25f * (p[0] + p[1] + p[WW] + p[WW + 1]);
        return;
    }
    int idx = (b - 1728) * 256 + threadIdx.x;   // 0..49151
    if (idx < 3104) {   // 388 halo positions x 8 threads x 8 c
        int pos = idx >> 3, cc = (idx & 7) * 8;
        int row, col;
        if (pos < 98)       { row = 0;             col = pos; }
        else if (pos < 196) { row = 97;            col = pos - 98; }
        else if (pos < 292) { row = pos - 196 + 1; col = 0; }
        else                { row = pos - 292 + 1; col = 97; }
        s16x8 zz = (s16x8){0, 0, 0, 0, 0, 0, 0, 0};
        *(s16x8*)(XTP + ((size_t)row * 98 + col) * 64 + cc) = zz;
    }
    int ci = idx & 63;
    int co = (idx >> 6) % 48;
    int kidx = idx / (48 * 64);
    float v = (ci < C) ? dw[((size_t)ci * C + co) * 16 + kidx] : 0.f;
    WB[idx] = f2bf(v);
}

// 5-group prep: g0->QB, g1->KB(+VT2 pad rows), g2..4->VT2 v-rows
__global__ void qkvprep_k(const float* __restrict__ xT,
                          const float* __restrict__ qw, const float* __restrict__ qb,
                          const float* __restrict__ kw, const float* __restrict__ kb,
                          const float* __restrict__ vw, const float* __restrict__ vb,
                          unsigned short* __restrict__ QB, unsigned short* __restrict__ KB,
                          unsigned short* __restrict__ VT2) {
    int tid = blockIdx.x * 256 + threadIdx.x;   // 5*9216 threads
    int p = tid % NP;
    int g = tid / NP;
    float f[C];
#pragma unroll
    for (int c4 = 0; c4 < C; c4 += 4) {
        f32x4 v = *(const f32x4*)(xT + (size_t)p * 48 + c4);
        f[c4] = v[0]; f[c4 + 1] = v[1]; f[c4 + 2] = v[2]; f[c4 + 3] = v[3];
    }
    int nt = p >> 4, nn = p & 15;
    if (g == 0) {
#pragma unroll
        for (int o = 0; o < 16; ++o) {
            float a = qb[o];
#pragma unroll
            for (int c = 0; c < C; ++c) a += qw[o * C + c] * f[c];
            QB[p * 16 + o] = f2bf(a);
        }
    } else if (g == 1) {
        const float L2E = 1.4426950408889634f;
#pragma unroll
        for (int o = 0; o < 16; ++o) {
            float a = kb[o];
#pragma unroll
            for (int c = 0; c < C; ++c) a += kw[o * C + c] * f[c];
            KB[p * 16 + o] = f2bf(a * L2E);
        }
        VT2[(size_t)nt * 1024 + 48 * 16 + nn] = 0x3F80;  // row 48 = ones (den)
#pragma unroll
        for (int r = 49; r < 64; ++r) VT2[(size_t)nt * 1024 + r * 16 + nn] = 0;
    } else {
        int c0 = (g - 2) * 16;
#pragma unroll
        for (int oo = 0; oo < 16; ++oo) {
            int o = c0 + oo;
            float a = vb[o];
#pragma unroll
            for (int c = 0; c < C; ++c) a += vw[o * C + c] * f[c];
            VT2[(size_t)nt * 1024 + o * 16 + nn] = f2bf(a);
        }
    }
}

#define MBLKS 72
#define NSPL  16
#define NSTEP 36   // 576 n per wave / 16

// 2-deep operand pipeline + 1-deep SCORE pipeline:
// loads 2 steps ahead; QK scores computed 1 step ahead (hides QK-MFMA latency
// under the previous step's PV MFMAs). Arithmetic identical per element.
// Tail over-reads (up to 2 tiles) stay inside d_ws; last tB is discarded unused.
template<int STEPS>
static __device__ __forceinline__ void attn_core32(const unsigned short* __restrict__ QB,
                                                   const unsigned short* __restrict__ VT2,
                                                   s16x4 bq0, s16x4 bq1, int n0, int lo, int hi,
                                                   f32x4 o0[4], f32x4 o1[4]) {
    const unsigned short* qp = QB + (size_t)(n0 + lo) * 16 + 4 * hi;
    const unsigned short* vp = VT2 + (size_t)(n0 >> 4) * 1024 + lo * 16 + 4 * hi;
    const f32x4 z = {0.f, 0.f, 0.f, 0.f};
    // stage A operands (step 0)
    s16x4 aqA  = *(const s16x4*)qp;
    s16x4 bvA0 = *(const s16x4*)(vp);
    s16x4 bvA1 = *(const s16x4*)(vp + 256);
    s16x4 bvA2 = *(const s16x4*)(vp + 512);
    s16x4 bvA3 = *(const s16x4*)(vp + 768);
    // stage B operands (step 1)
    qp += 256; vp += 1024;
    s16x4 aqB  = *(const s16x4*)qp;
    s16x4 bvB0 = *(const s16x4*)(vp);
    s16x4 bvB1 = *(const s16x4*)(vp + 256);
    s16x4 bvB2 = *(const s16x4*)(vp + 512);
    s16x4 bvB3 = *(const s16x4*)(vp + 768);
    // scores for step 0
    f32x4 tA0 = mfma16(aqA, bq0, z);
    f32x4 tA1 = mfma16(aqA, bq1, z);

    for (int s = 0; s < STEPS; ++s) {
        qp += 256; vp += 1024;
        // issue loads for step s+2
        s16x4 aqn  = *(const s16x4*)qp;
        s16x4 bvn0 = *(const s16x4*)(vp);
        s16x4 bvn1 = *(const s16x4*)(vp + 256);
        s16x4 bvn2 = *(const s16x4*)(vp + 512);
        s16x4 bvn3 = *(const s16x4*)(vp + 768);

        // scores for step s+1 (independent of this step's softmax/PV)
        f32x4 tB0 = mfma16(aqB, bq0, z);
        f32x4 tB1 = mfma16(aqB, bq1, z);

        // softmax + PV for step s (scores tA, V = bvA)
        s16x4 p0 = pack_bf16x4(fexp2(tA0[0]), fexp2(tA0[1]), fexp2(tA0[2]), fexp2(tA0[3]));
        s16x4 p1 = pack_bf16x4(fexp2(tA1[0]), fexp2(tA1[1]), fexp2(tA1[2]), fexp2(tA1[3]));
        o0[0] = mfma16(p0, bvA0, o0[0]);
        o0[1] = mfma16(p0, bvA1, o0[1]);
        o0[2] = mfma16(p0, bvA2, o0[2]);
        o0[3] = mfma16(p0, bvA3, o0[3]);
        o1[0] = mfma16(p1, bvA0, o1[0]);
        o1[1] = mfma16(p1, bvA1, o1[1]);
        o1[2] = mfma16(p1, bvA2, o1[2]);
        o1[3] = mfma16(p1, bvA3, o1[3]);

        // rotate: scores B->A, operands B->A, new->B
        tA0 = tB0; tA1 = tB1;
        bvA0 = bvB0; bvA1 = bvB1; bvA2 = bvB2; bvA3 = bvB3;
        aqB = aqn; bvB0 = bvn0; bvB1 = bvn1; bvB2 = bvn2; bvB3 = bvn3;
    }
}

// Atomic-free attn: 32m per wave, NSPL=16 (1152 blocks). launch_bounds(256,2) — FROZEN.
__global__ __launch_bounds__(256, 2) void attn_k(const unsigned short* __restrict__ QB,
                                                 const unsigned short* __restrict__ KB,
                                                 const unsigned short* __restrict__ VT2,
                                                 unsigned short* __restrict__ PART) {
    const int lane = threadIdx.x & 63;
    const int lo = lane & 15, hi = lane >> 4;
    const int wv = threadIdx.x >> 6;
    const int mblk = blockIdx.x % MBLKS;
    const int nspl = blockIdx.x / MBLKS;
    const int mt0 = mblk * 128 + wv * 32;

    const s16x4 bq0 = *(const s16x4*)(KB + (size_t)(mt0 + lo) * 16 + 4 * hi);
    const s16x4 bq1 = *(const s16x4*)(KB + (size_t)(mt0 + 16 + lo) * 16 + 4 * hi);

    f32x4 o0[4], o1[4];
#pragma unroll
    for (int i = 0; i < 4; ++i) {
        o0[i] = (f32x4){0.f, 0.f, 0.f, 0.f};
        o1[i] = (f32x4){0.f, 0.f, 0.f, 0.f};
    }
    attn_core32<NSTEP>(QB, VT2, bq0, bq1, nspl * (NP / NSPL), lo, hi, o0, o1);

    unsigned short* cp = PART + ((size_t)(mblk * 4 + wv) * NSPL + nspl) * 2048;
#pragma unroll
    for (int q = 0; q < 8; ++q) {
        const f32x4& o = (q >> 2) ? o1[q & 3] : o0[q & 3];
        s16x4 pk = pack_bf16x4(o[0], o[1], o[2], o[3]);
        *(s16x4*)(cp + q * 256 + lane * 4) = pk;
    }
}

// Reduce 16 chunks + epilogue. 576 blocks = 288 tiles x 2 halves (R18-proven).
__global__ __launch_bounds__(256) void reduce_epi_k(const unsigned short* __restrict__ PART,
                                                    const float* __restrict__ xT,
                                                    const float* __restrict__ gamma,
                                                    unsigned short* __restrict__ XTP) {
    __shared__ float sden[32];
    const int B = blockIdx.x;
    const int T = B >> 1, half = B & 1;
    const int mt0 = (T >> 2) * 128 + (T & 3) * 32;
    const unsigned short* base = PART + (size_t)T * NSPL * 2048;
    const int t = threadIdx.x;

    if (t < 8) {   // den: c=48 -> ct=3, lo=0; groups (h,hi)
        int h = t >> 2, hi = t & 3;
        int idx = (h * 4 + 3) * 256 + (hi * 16) * 4;
        float a0 = 0.f, a1 = 0.f, a2 = 0.f, a3 = 0.f;
        for (int ns = 0; ns < NSPL; ++ns) {
            s16x4 v = *(const s16x4*)(base + ns * 2048 + idx);
            a0 += bf2f((unsigned short)v[0]);
            a1 += bf2f((unsigned short)v[1]);
            a2 += bf2f((unsigned short)v[2]);
            a3 += bf2f((unsigned short)v[3]);
        }
        sden[h * 16 + hi * 4 + 0] = a0;
        sden[h * 16 + hi * 4 + 1] = a1;
        sden[h * 16 + hi * 4 + 2] = a2;
        sden[h * 16 + hi * 4 + 3] = a3;
    }
    __syncthreads();

    float gam = gamma[0];
    int g = half * 256 + t;
    int q = g >> 6, lane = g & 63;
    int h = q >> 2, ct = q & 3;
    int hi = lane >> 4, lo = lane & 15;
    int c = ct * 16 + lo;
    int idx = q * 256 + lane * 4;
    float a0 = 0.f, a1 = 0.f, a2 = 0.f, a3 = 0.f;
    for (int ns = 0; ns < NSPL; ++ns) {
        s16x4 v = *(const s16x4*)(base + ns * 2048 + idx);
        a0 += bf2f((unsigned short)v[0]);
        a1 += bf2f((unsigned short)v[1]);
        a2 += bf2f((unsigned short)v[2]);
        a3 += bf2f((unsigned short)v[3]);
    }
    if (c < 48) {
        float av[4] = {a0, a1, a2, a3};
#pragma unroll
        for (int j = 0; j < 4; ++j) {
            int ml = h * 16 + hi * 4 + j;
            int m = mt0 + ml;
            float val = gam * av[j] / sden[ml] + xT[(size_t)m * 48 + c];
            int iy = m / WP, ix = m % WP;
            XTP[((size_t)(iy + 1) * 98 + ix + 1) * 64 + c] = f2bf(val);
        }
    }
}

// ---------- fallback path (small ws): atomics into O4 (overlays PART) ----------
__global__ __launch_bounds__(256) void attn_atomic_k(const unsigned short* __restrict__ QB,
                                                     const unsigned short* __restrict__ KB,
                                                     const unsigned short* __restrict__ VT2,
                                                     float* __restrict__ O4) {
    const int lane = threadIdx.x & 63;
    const int lo = lane & 15, hi = lane >> 4;
    const int wv = threadIdx.x >> 6;
    const int mblk = blockIdx.x % 72;
    const int nspl = blockIdx.x / 72;
    const int mt0 = mblk * 128 + wv * 32;
    const s16x4 bq0 = *(const s16x4*)(KB + (size_t)(mt0 + lo) * 16 + 4 * hi);
    const s16x4 bq1 = *(const s16x4*)(KB + (size_t)(mt0 + 16 + lo) * 16 + 4 * hi);
    f32x4 o0[4], o1[4];
#pragma unroll
    for (int i = 0; i < 4; ++i) {
        o0[i] = (f32x4){0.f, 0.f, 0.f, 0.f};
        o1[i] = (f32x4){0.f, 0.f, 0.f, 0.f};
    }
    attn_core32<18>(QB, VT2, bq0, bq1, nspl * 288, lo, hi, o0, o1);
    float* Oc = O4 + (size_t)(nspl & 3) * (NP * 64);
#pragma unroll
    for (int ct = 0; ct < 4; ++ct)
#pragma unroll
        for (int j = 0; j < 4; ++j) {
            atomicAdd(&Oc[(size_t)(mt0 + 4 * hi + j) * 64 + 16 * ct + lo], o0[ct][j]);
            atomicAdd(&Oc[(size_t)(mt0 + 16 + 4 * hi + j) * 64 + 16 * ct + lo], o1[ct][j]);
        }
}

__global__ void epi_atomic_k(const float* __restrict__ O4, const float* __restrict__ xT,
                             const float* __restrict__ gamma, unsigned short* __restrict__ XTP) {
    int m = blockIdx.x * 256 + threadIdx.x;
    if (m >= NP) return;
    int iy = m / WP, ix = m % WP;
    unsigned short* xp = XTP + ((size_t)(iy + 1) * 98 + ix + 1) * 64;
    float den = 0.f;
#pragma unroll
    for (int cp = 0; cp < 4; ++cp) den += O4[(size_t)cp * (NP * 64) + (size_t)m * 64 + 48];
    float rg = gamma[0] / den;
#pragma unroll
    for (int c = 0; c < C; ++c) {
        float o = 0.f;
#pragma unroll
        for (int cp = 0; cp < 4; ++cp) o += O4[(size_t)cp * (NP * 64) + (size_t)m * 64 + c];
        xp[c] = f2bf(rg * o + xT[(size_t)m * 48 + c]);
    }
}

// ConvTranspose2d via MFMA; one 16-ox tile per wave (1152 blocks).
__global__ __launch_bounds__(128) void convt_mfma_k(const unsigned short* __restrict__ XTP,
                                                    const unsigned short* __restrict__ WB,
                                                    const float* __restrict__ db,
                                                    float* __restrict__ y) {
    const int lane = threadIdx.x & 63;
    const int lo = lane & 15, hi = lane >> 4;
    const int wv = threadIdx.x >> 6;   // 0..1
    const int b = blockIdx.x;          // 96*2*2*3
    const int i3 = b % 3;
    const int r3 = b / 3;
    const int px = r3 & 1;
    const int py = (r3 >> 1) & 1;
    const int oyp = r3 >> 2;

    const int sy[2] = {0, py ? 1 : -1};
    const int kyt[2] = {py ? 2 : 1, py ? 0 : 3};
    const int sx[2] = {0, px ? 1 : -1};
    const int kxt[2] = {px ? 2 : 1, px ? 0 : 3};

    s16x8 bw[2][2][2][3];  // [ty][tx][kk][ct]
#pragma unroll
    for (int ty = 0; ty < 2; ++ty)
#pragma unroll
        for (int tx = 0; tx < 2; ++tx) {
            const unsigned short* wp = WB + (size_t)(kyt[ty] * 4 + kxt[tx]) * 48 * 64;
#pragma unroll
            for (int kk = 0; kk < 2; ++kk)
#pragma unroll
                for (int ct = 0; ct < 3; ++ct)
                    bw[ty][tx][kk][ct] = *(const s16x8*)(wp + (size_t)(ct * 16 + lo) * 64 + kk * 32 + 8 * hi);
        }
    float bias[3];
#pragma unroll
    for (int ct = 0; ct < 3; ++ct) bias[ct] = db[ct * 16 + lo];

    const int oy = 2 * oyp + py;
    const int ox0 = (wv * 3 + i3) * 16;
    f32x4 acc[3];
#pragma unroll
    for (int ct = 0; ct < 3; ++ct) acc[ct] = (f32x4){bias[ct], bias[ct], bias[ct], bias[ct]};
#pragma unroll
    for (int ty = 0; ty < 2; ++ty) {
        int R0 = (oyp + sy[ty] + 1) * 98;
#pragma unroll
        for (int tx = 0; tx < 2; ++tx) {
            const unsigned short* ap = XTP + (size_t)(R0 + ox0 + sx[tx] + 1 + lo) * 64 + 8 * hi;
#pragma unroll
            for (int kk = 0; kk < 2; ++kk) {
                s16x8 a = *(const s16x8*)(ap + kk * 32);
                acc[0] = mfma32(a, bw[ty][tx][kk][0], acc[0]);
                acc[1] = mfma32(a, bw[ty][tx][kk][1], acc[1]);
                acc[2] = mfma32(a, bw[ty][tx][kk][2], acc[2]);
            }
        }
    }
#pragma unroll
    for (int ct = 0; ct < 3; ++ct)
#pragma unroll
        for (int j = 0; j < 4; ++j)
            y[(size_t)(ct * 16 + lo) * (HH * WW) + oy * WW + 2 * (ox0 + 4 * hi + j) + px] = acc[ct][j];
}

extern "C" void kernel_launch(void* const* d_in, const int* in_sizes, int n_in,
                              void* d_out, int out_size, void* d_ws, size_t ws_size,
                              hipStream_t stream) {
    const float* in    = (const float*)d_in[0];
    const float* qw    = (const float*)d_in[1];
    const float* qb    = (const float*)d_in[2];
    const float* kw    = (const float*)d_in[3];
    const float* kb    = (const float*)d_in[4];
    const float* vw    = (const float*)d_in[5];
    const float* vb    = (const float*)d_in[6];
    const float* gamma = (const float*)d_in[7];
    const float* dw    = (const float*)d_in[8];
    const float* db    = (const float*)d_in[9];
    float* out = (float*)d_out;

    float* ws = (float*)d_ws;
    unsigned short* QB   = (unsigned short*)(ws + OFF_QB);
    unsigned short* KB   = (unsigned short*)(ws + OFF_KB);
    unsigned short* VT2  = (unsigned short*)(ws + OFF_VT2);
    float*          xT   = ws + OFF_XT;
    unsigned short* XTP  = (unsigned short*)(ws + OFF_XTP);
    unsigned short* WB   = (unsigned short*)(ws + OFF_WB);
    unsigned short* PART = (unsigned short*)(ws + OFF_PART);

    pool_wprep_k<<<1920, 256, 0, stream>>>(in, xT, dw, WB, XTP);
    qkvprep_k<<<(5 * NP) / 256, 256, 0, stream>>>(xT, qw, qb, kw, kb, vw, vb, QB, KB, VT2);

    if (ws_size >= WS_NEED_BYTES) {
        attn_k<<<MBLKS * NSPL, 256, 0, stream>>>(QB, KB, VT2, PART);
        reduce_epi_k<<<576, 256, 0, stream>>>(PART, xT, gamma, XTP);
    } else {
        float* O4 = (float*)PART;   // overlays PART region
        hipMemsetAsync(O4, 0, (size_t)4 * NP * 64 * sizeof(float), stream);
        attn_atomic_k<<<72 * 32, 256, 0, stream>>>(QB, KB, VT2, O4);
        epi_atomic_k<<<(NP + 255) / 256, 256, 0, stream>>>(O4, xT, gamma, XTP);
    }
    convt_mfma_k<<<96 * 2 * 2 * 3, 128, 0, stream>>>(XTP, WB, db, out);
}